// Round 4
// baseline (985.241 us; speedup 1.0000x reference)
//
#include <hip/hip_runtime.h>
#include <hip/hip_bf16.h>
#include <math.h>

#define NN 50000
#define NE 800000
#define NR 16
#define DD 64
#define OSTRIDE 192   // 3*D concat output stride

__device__ inline float tanh_fast(float x) {
    // 1 - 2/(e^{2x}+1); exact limits at +/-inf, ~1e-7 abs err
    return 1.f - 2.f / (__expf(2.f * x) + 1.f);
}

// ---------- CSR build + per-node relation mask ----------
__global__ void k_deg(const int* __restrict__ dst, const int* __restrict__ rel,
                      int* __restrict__ cnt, int* __restrict__ relmask) {
    for (int e = blockIdx.x * blockDim.x + threadIdx.x; e < NE;
         e += gridDim.x * blockDim.x) {
        int d = dst[e];
        atomicAdd(&cnt[d], 1);
        if (relmask) atomicOr(&relmask[d], 1 << rel[e]);
    }
}

__global__ __launch_bounds__(1024) void k_scan(int* __restrict__ cnt,
                                               int* __restrict__ rowptr) {
    __shared__ int part[1024];
    int t = threadIdx.x;
    const int CH = (NN + 1023) / 1024;
    int lo = t * CH, hi = lo + CH > NN ? NN : lo + CH;
    int s = 0;
    for (int i = lo; i < hi; ++i) s += cnt[i];
    part[t] = s;
    __syncthreads();
    for (int o = 1; o < 1024; o <<= 1) {
        int v = (t >= o) ? part[t - o] : 0;
        __syncthreads();
        part[t] += v;
        __syncthreads();
    }
    int run = (t == 0) ? 0 : part[t - 1];
    for (int i = lo; i < hi; ++i) {
        int d = cnt[i];
        rowptr[i] = run;
        cnt[i] = run;        // fill cursor
        run += d;
    }
    if (t == 1023) rowptr[NN] = run;
}

// epack[pos] = src | (rel<<16)  (src < 65536, rel < 16)
__global__ void k_fill(const int* __restrict__ dst, const int* __restrict__ src,
                       const int* __restrict__ rel, int* __restrict__ cursor,
                       int* __restrict__ epack) {
    for (int e = blockIdx.x * blockDim.x + threadIdx.x; e < NE;
         e += gridDim.x * blockDim.x) {
        int pos = atomicAdd(&cursor[dst[e]], 1);
        epack[pos] = src[e] | (rel[e] << 16);
    }
}

// ---------- h0 gather ----------
__global__ void k_copy_h0(const int* __restrict__ node_ids,
                          const float* __restrict__ ent,
                          float* __restrict__ out) {
    int i = blockIdx.x * blockDim.x + threadIdx.x;
    if (i >= NN * DD) return;
    int n = i >> 6, d = i & 63;
    out[(size_t)n * OSTRIDE + d] = ent[(size_t)node_ids[n] * DD + d];
}

// ---------- fused double GEMM: q[n,r,:] = W_r @ tanh(h[n,:]@W_r + e_r) ----------
// 64 nodes/block, 16 relations sequentially. trans never hits HBM.
__global__ __launch_bounds__(256) void k_transq(const float* __restrict__ outbuf, int off_in,
                                                const float* __restrict__ W,
                                                const float* __restrict__ relE,
                                                const int* __restrict__ relmask,
                                                float* __restrict__ q) {
    __shared__ float hs[64][68];    // h^T: hs[d][n]
    __shared__ float us[64][68];    // U^T: us[E][n]
    __shared__ float ws[64][64];    // W_r [d][E]
    __shared__ float wts[64][68];   // W_r^T [E][d]
    int t = threadIdx.x;
    int n0 = blockIdx.x * 64;

    for (int i = t; i < 1024; i += 256) {
        int ni = i >> 4, c4 = (i & 15) * 4;
        int n = n0 + ni;
        float4 v = make_float4(0.f, 0.f, 0.f, 0.f);
        if (n < NN) v = *(const float4*)&outbuf[(size_t)n * OSTRIDE + off_in + c4];
        hs[c4 + 0][ni] = v.x;
        hs[c4 + 1][ni] = v.y;
        hs[c4 + 2][ni] = v.z;
        hs[c4 + 3][ni] = v.w;
    }

    int nd0 = (t >> 4) * 4;      // 4 nodes
    int c0  = (t & 15) * 4;      // 4 cols
    int mask[4];
    #pragma unroll
    for (int i = 0; i < 4; ++i) {
        int n = n0 + nd0 + i;
        mask[i] = (n < NN) ? (relmask ? relmask[n] : 0xffff) : 0;
    }

    for (int r = 0; r < NR; ++r) {
        __syncthreads();   // prev iter readers of ws/wts done (covers hs staging on r=0)
        const float* Wr = W + r * 4096;
        for (int i = t; i < 1024; i += 256) {
            float4 v = *(const float4*)&Wr[i * 4];
            int d = i >> 4, e4 = (i & 15) * 4;
            *(float4*)&ws[d][e4] = v;
            wts[e4 + 0][d] = v.x;
            wts[e4 + 1][d] = v.y;
            wts[e4 + 2][d] = v.z;
            wts[e4 + 3][d] = v.w;
        }
        __syncthreads();

        // GEMM1: T[n, E] = sum_d h[n,d] * W[d,E]   (n = nd0..+3, E = c0..+3)
        float acc[4][4] = {};
        #pragma unroll 8
        for (int k = 0; k < 64; ++k) {
            float4 h4 = *(const float4*)&hs[k][nd0];
            float4 w4 = *(const float4*)&ws[k][c0];
            float hh[4] = {h4.x, h4.y, h4.z, h4.w};
            #pragma unroll
            for (int i = 0; i < 4; ++i) {
                acc[i][0] += hh[i] * w4.x; acc[i][1] += hh[i] * w4.y;
                acc[i][2] += hh[i] * w4.z; acc[i][3] += hh[i] * w4.w;
            }
        }
        // U = tanh(T + e_r), store transposed
        float4 er = *(const float4*)&relE[r * DD + c0];
        float ee[4] = {er.x, er.y, er.z, er.w};
        #pragma unroll
        for (int i = 0; i < 4; ++i)
            #pragma unroll
            for (int j = 0; j < 4; ++j)
                us[c0 + j][nd0 + i] = tanh_fast(acc[i][j] + ee[j]);
        __syncthreads();

        // GEMM2: Q[n, d] = sum_E U[n,E] * W[d,E]   (d = c0..+3, k = E)
        float qa[4][4] = {};
        #pragma unroll 8
        for (int k = 0; k < 64; ++k) {
            float4 u4 = *(const float4*)&us[k][nd0];
            float4 w4 = *(const float4*)&wts[k][c0];
            float uu[4] = {u4.x, u4.y, u4.z, u4.w};
            #pragma unroll
            for (int i = 0; i < 4; ++i) {
                qa[i][0] += uu[i] * w4.x; qa[i][1] += uu[i] * w4.y;
                qa[i][2] += uu[i] * w4.z; qa[i][3] += uu[i] * w4.w;
            }
        }
        #pragma unroll
        for (int i = 0; i < 4; ++i) {
            if ((mask[i] >> r) & 1) {
                int n = n0 + nd0 + i;
                *(float4*)&q[(((size_t)n) * NR + r) * DD + c0] =
                    make_float4(qa[i][0], qa[i][1], qa[i][2], qa[i][3]);
            }
        }
    }
}

// ---------- fused attention + softmax + aggregate (one wave per dst node) ----------
// att[e] = h[src] . q[dst, r]; own q rows are L1-hot, only h[src] is gathered.
__global__ __launch_bounds__(256) void k_fused2(const float* __restrict__ q,
                                                const float* __restrict__ hbuf, int off_in,
                                                const int* __restrict__ rowptr,
                                                const int* __restrict__ epack,
                                                float* __restrict__ h_nb) {
    int n = blockIdx.x * 4 + (threadIdx.x >> 6);
    if (n >= NN) return;
    int lane = threadIdx.x & 63;
    int row0 = rowptr[n], row1 = rowptr[n + 1];
    int deg = row1 - row0;

    const float* qn = q + ((size_t)n) * NR * DD;
    float m = -__builtin_inff(), z = 0.f, acc = 0.f;

    int p = (deg > 0) ? epack[row0] : 0;
    for (int i = 0; i < deg; ++i) {
        int s = p & 0xffff;
        int r = p >> 16;
        float qv  = qn[r * DD + lane];
        float hsv = hbuf[(size_t)s * OSTRIDE + off_in + lane];
        if (i + 1 < deg) p = epack[row0 + i + 1];
        float v = hsv * qv;
        #pragma unroll
        for (int o = 32; o; o >>= 1) v += __shfl_xor(v, o, 64);
        float mn = fmaxf(m, v);
        float sc = __expf(m - mn);
        float w  = __expf(v - mn);
        z   = z * sc + w;
        acc = acc * sc + w * hsv;
        m = mn;
    }
    h_nb[(size_t)n * DD + lane] = (deg > 0) ? acc / z : 0.f;
}

// ---------- epilogue GEMM ----------
__global__ __launch_bounds__(256) void k_out2(const float* __restrict__ h_nb,
                                              const float* __restrict__ ra,
                                              const float* __restrict__ rb,
                                              float* __restrict__ out,
                                              int off_in, int off_out) {
    __shared__ float v1s[64][68];
    __shared__ float v2s[64][68];
    __shared__ float ws[2][64][64];
    int t = threadIdx.x;
    int n0 = blockIdx.x * 64;

    for (int i = t; i < 1024; i += 256) {
        int ni = i >> 4, c4 = (i & 15) * 4;
        int n = n0 + ni;
        float4 hv = make_float4(0.f, 0.f, 0.f, 0.f);
        float4 nb = make_float4(0.f, 0.f, 0.f, 0.f);
        if (n < NN) {
            hv = *(const float4*)&out[(size_t)n * OSTRIDE + off_in + c4];
            nb = *(const float4*)&h_nb[(size_t)n * DD + c4];
        }
        v1s[c4 + 0][ni] = hv.x + nb.x;  v2s[c4 + 0][ni] = hv.x * nb.x;
        v1s[c4 + 1][ni] = hv.y + nb.y;  v2s[c4 + 1][ni] = hv.y * nb.y;
        v1s[c4 + 2][ni] = hv.z + nb.z;  v2s[c4 + 2][ni] = hv.z * nb.z;
        v1s[c4 + 3][ni] = hv.w + nb.w;  v2s[c4 + 3][ni] = hv.w * nb.w;
    }
    for (int i = t; i < 2048; i += 256) {
        const float* base = (i < 1024) ? ra : rb;
        int rem = i & 1023;
        float4 v = *(const float4*)&base[rem * 4];
        int k = rem >> 4, c4 = (rem & 15) * 4;
        *(float4*)&ws[i >> 10][k][c4] = v;
    }
    __syncthreads();

    int nd0 = (t >> 4) * 4;
    int c0  = (t & 15) * 4;
    float a1[4][4] = {}, a2[4][4] = {};
    #pragma unroll 8
    for (int k = 0; k < 64; ++k) {
        float4 h1 = *(const float4*)&v1s[k][nd0];
        float4 h2 = *(const float4*)&v2s[k][nd0];
        float4 wa = *(const float4*)&ws[0][k][c0];
        float4 wb = *(const float4*)&ws[1][k][c0];
        float x1[4] = {h1.x, h1.y, h1.z, h1.w};
        float x2[4] = {h2.x, h2.y, h2.z, h2.w};
        #pragma unroll
        for (int i = 0; i < 4; ++i) {
            a1[i][0] += x1[i] * wa.x; a1[i][1] += x1[i] * wa.y;
            a1[i][2] += x1[i] * wa.z; a1[i][3] += x1[i] * wa.w;
            a2[i][0] += x2[i] * wb.x; a2[i][1] += x2[i] * wb.y;
            a2[i][2] += x2[i] * wb.z; a2[i][3] += x2[i] * wb.w;
        }
    }
    #pragma unroll
    for (int i = 0; i < 4; ++i) {
        int n = n0 + nd0 + i;
        if (n >= NN) continue;
        float4 o;
        float* po = (float*)&o;
        #pragma unroll
        for (int j = 0; j < 4; ++j) {
            float u1 = a1[i][j], u2 = a2[i][j];
            u1 = u1 > 0.f ? u1 : 0.01f * u1;
            u2 = u2 > 0.f ? u2 : 0.01f * u2;
            po[j] = u1 + u2;
        }
        *(float4*)&out[(size_t)n * OSTRIDE + off_out + c0] = o;
    }
}

// ---------- launch ----------
extern "C" void kernel_launch(void* const* d_in, const int* in_sizes, int n_in,
                              void* d_out, int out_size, void* d_ws, size_t ws_size,
                              hipStream_t stream) {
    const int*   node_ids = (const int*)d_in[0];
    const int*   rel_ids  = (const int*)d_in[1];
    const int*   src      = (const int*)d_in[2];
    const int*   dst      = (const int*)d_in[3];
    const float* ent      = (const float*)d_in[4];
    const float* relE     = (const float*)d_in[5];
    const float* W[2]  = {(const float*)d_in[6], (const float*)d_in[7]};
    const float* ra[2] = {(const float*)d_in[8], (const float*)d_in[10]};
    const float* rb[2] = {(const float*)d_in[9], (const float*)d_in[11]};
    float* out = (float*)d_out;

    const size_t q_bytes      = (size_t)NN * NR * DD * sizeof(float);  // 204.8 MB
    const size_t hnb_bytes    = (size_t)NN * DD * sizeof(float);       // 12.8 MB
    const size_t epack_bytes  = (size_t)NE * sizeof(int);              // 3.2 MB
    const size_t rowptr_bytes = (size_t)(NN + 1) * sizeof(int);
    const size_t cnt_bytes    = (size_t)NN * sizeof(int);
    const size_t mask_bytes   = (size_t)NN * sizeof(int);

    char* p = (char*)d_ws;
    float* q      = (float*)p; p += q_bytes;
    float* h_nb   = (float*)p; p += hnb_bytes;
    int*   epack  = (int*)p;   p += epack_bytes;
    int*   rowptr = (int*)p;   p += rowptr_bytes;
    int*   cnt    = (int*)p;   p += cnt_bytes;
    size_t used = (size_t)(p - (char*)d_ws);
    int* relmask = (used + mask_bytes <= ws_size) ? (int*)p : nullptr;

    // ---- CSR build (shared by both layers) ----
    hipMemsetAsync(cnt, 0, cnt_bytes, stream);
    if (relmask) hipMemsetAsync(relmask, 0, mask_bytes, stream);
    k_deg <<<1024, 256, 0, stream>>>(dst, rel_ids, cnt, relmask);
    k_scan<<<1, 1024, 0, stream>>>(cnt, rowptr);
    k_fill<<<1024, 256, 0, stream>>>(dst, src, rel_ids, cnt, epack);

    // ---- h0 ----
    k_copy_h0<<<(NN * DD + 255) / 256, 256, 0, stream>>>(node_ids, ent, out);

    for (int L = 0; L < 2; ++L) {
        int off_in = L * DD;
        int off_out = (L + 1) * DD;

        k_transq<<<(NN + 63) / 64, 256, 0, stream>>>(out, off_in, W[L], relE,
                                                     relmask, q);
        k_fused2<<<(NN + 3) / 4, 256, 0, stream>>>(q, out, off_in,
                                                   rowptr, epack, h_nb);
        k_out2  <<<(NN + 63) / 64, 256, 0, stream>>>(h_nb, ra[L], rb[L], out,
                                                     off_in, off_out);
    }
}

// Round 5
// 874.191 us; speedup vs baseline: 1.1270x; 1.1270x over previous
//
#include <hip/hip_runtime.h>
#include <hip/hip_bf16.h>
#include <math.h>

#define NN 50000
#define NE 800000
#define NR 16
#define DD 64
#define OSTRIDE 192   // 3*D concat output stride

__device__ inline float tanh_fast(float x) {
    return 1.f - 2.f / (__expf(2.f * x) + 1.f);
}

// ---------- CSR build + per-node relation mask ----------
__global__ void k_deg(const int* __restrict__ dst, const int* __restrict__ rel,
                      int* __restrict__ cnt, int* __restrict__ relmask) {
    for (int e = blockIdx.x * blockDim.x + threadIdx.x; e < NE;
         e += gridDim.x * blockDim.x) {
        int d = dst[e];
        atomicAdd(&cnt[d], 1);
        if (relmask) atomicOr(&relmask[d], 1 << rel[e]);
    }
}

__global__ __launch_bounds__(1024) void k_scan(int* __restrict__ cnt,
                                               int* __restrict__ rowptr) {
    __shared__ int part[1024];
    int t = threadIdx.x;
    const int CH = (NN + 1023) / 1024;
    int lo = t * CH, hi = lo + CH > NN ? NN : lo + CH;
    int s = 0;
    for (int i = lo; i < hi; ++i) s += cnt[i];
    part[t] = s;
    __syncthreads();
    for (int o = 1; o < 1024; o <<= 1) {
        int v = (t >= o) ? part[t - o] : 0;
        __syncthreads();
        part[t] += v;
        __syncthreads();
    }
    int run = (t == 0) ? 0 : part[t - 1];
    for (int i = lo; i < hi; ++i) {
        int d = cnt[i];
        rowptr[i] = run;
        cnt[i] = run;        // fill cursor
        run += d;
    }
    if (t == 1023) rowptr[NN] = run;
}

// epack[pos] = src | (rel<<16)
__global__ void k_fill(const int* __restrict__ dst, const int* __restrict__ src,
                       const int* __restrict__ rel, int* __restrict__ cursor,
                       int* __restrict__ epack) {
    for (int e = blockIdx.x * blockDim.x + threadIdx.x; e < NE;
         e += gridDim.x * blockDim.x) {
        int pos = atomicAdd(&cursor[dst[e]], 1);
        epack[pos] = src[e] | (rel[e] << 16);
    }
}

// ---------- h0 gather ----------
__global__ void k_copy_h0(const int* __restrict__ node_ids,
                          const float* __restrict__ ent,
                          float* __restrict__ out) {
    int i = blockIdx.x * blockDim.x + threadIdx.x;
    if (i >= NN * DD) return;
    int n = i >> 6, d = i & 63;
    out[(size_t)n * OSTRIDE + d] = ent[(size_t)node_ids[n] * DD + d];
}

// ---------- q[n,r,:] = W_r @ tanh(h[n,:]@W_r + e_r) ----------
// Per-relation blocks: grid (tiles, NR), 512 threads, 64-node tile, 2 barriers.
// All LDS row-natural, stride 68 (16B-aligned rows, conflict-free access):
//   GEMM k-loops: b128 broadcast of ws[k]/wts[k] + 2 scalar broadcast node reads.
__global__ __launch_bounds__(512) void k_transq2(const float* __restrict__ outbuf, int off_in,
                                                 const float* __restrict__ W,
                                                 const float* __restrict__ relE,
                                                 const int* __restrict__ relmask,
                                                 float* __restrict__ q) {
    __shared__ __align__(16) float hs2[64][68];  // h  [node][d]
    __shared__ __align__(16) float us2[64][68];  // U  [node][E]
    __shared__ __align__(16) float ws [64][68];  // W_r [d][E]
    __shared__ __align__(16) float wts[64][68];  // W_r^T [E][d]
    int t = threadIdx.x;
    int n0 = blockIdx.x * 64;
    int r  = blockIdx.y;

    // stage h tile + W_r + W_r^T
    const float* Wr = W + r * 4096;
    #pragma unroll
    for (int ii = 0; ii < 2; ++ii) {
        int i = t + ii * 512;
        int a = i >> 4, c4 = (i & 15) * 4;
        int n = n0 + a;
        float4 hv = make_float4(0.f, 0.f, 0.f, 0.f);
        if (n < NN) hv = *(const float4*)&outbuf[(size_t)n * OSTRIDE + off_in + c4];
        *(float4*)&hs2[a][c4] = hv;
        float4 wv = *(const float4*)&Wr[i * 4];
        *(float4*)&ws[a][c4] = wv;
        wts[c4 + 0][a] = wv.x;
        wts[c4 + 1][a] = wv.y;
        wts[c4 + 2][a] = wv.z;
        wts[c4 + 3][a] = wv.w;
    }
    __syncthreads();

    int c0  = (t & 15) * 4;       // 4 cols
    int nd0 = (t >> 4) * 2;       // 2 nodes

    // GEMM1: T[n,E] = sum_d h[n,d] * W[d,E];  U = tanh(T + e_r)
    float acc[2][4] = {};
    #pragma unroll 8
    for (int k = 0; k < 64; ++k) {
        float4 w4 = *(const float4*)&ws[k][c0];
        float h0 = hs2[nd0][k];
        float h1 = hs2[nd0 + 1][k];
        acc[0][0] += h0 * w4.x; acc[0][1] += h0 * w4.y;
        acc[0][2] += h0 * w4.z; acc[0][3] += h0 * w4.w;
        acc[1][0] += h1 * w4.x; acc[1][1] += h1 * w4.y;
        acc[1][2] += h1 * w4.z; acc[1][3] += h1 * w4.w;
    }
    float4 er = *(const float4*)&relE[r * DD + c0];
    float ee[4] = {er.x, er.y, er.z, er.w};
    #pragma unroll
    for (int i = 0; i < 2; ++i) {
        float4 u;
        u.x = tanh_fast(acc[i][0] + ee[0]);
        u.y = tanh_fast(acc[i][1] + ee[1]);
        u.z = tanh_fast(acc[i][2] + ee[2]);
        u.w = tanh_fast(acc[i][3] + ee[3]);
        *(float4*)&us2[nd0 + i][c0] = u;
    }
    __syncthreads();

    // GEMM2: Q[n,d] = sum_E U[n,E] * W[d,E]  (wts[E][d] rows broadcast)
    float qa[2][4] = {};
    #pragma unroll 8
    for (int k = 0; k < 64; ++k) {
        float4 w4 = *(const float4*)&wts[k][c0];
        float u0 = us2[nd0][k];
        float u1 = us2[nd0 + 1][k];
        qa[0][0] += u0 * w4.x; qa[0][1] += u0 * w4.y;
        qa[0][2] += u0 * w4.z; qa[0][3] += u0 * w4.w;
        qa[1][0] += u1 * w4.x; qa[1][1] += u1 * w4.y;
        qa[1][2] += u1 * w4.z; qa[1][3] += u1 * w4.w;
    }
    #pragma unroll
    for (int i = 0; i < 2; ++i) {
        int n = n0 + nd0 + i;
        if (n < NN) {
            int m = relmask ? relmask[n] : 0xffff;
            if ((m >> r) & 1)
                *(float4*)&q[(((size_t)n) * NR + r) * DD + c0] =
                    make_float4(qa[i][0], qa[i][1], qa[i][2], qa[i][3]);
        }
    }
}

// ---------- fused attention + softmax + aggregate (one wave per dst node) ----------
__global__ __launch_bounds__(256) void k_fused2(const float* __restrict__ q,
                                                const float* __restrict__ hbuf, int off_in,
                                                const int* __restrict__ rowptr,
                                                const int* __restrict__ epack,
                                                float* __restrict__ h_nb) {
    int n = blockIdx.x * 4 + (threadIdx.x >> 6);
    if (n >= NN) return;
    int lane = threadIdx.x & 63;
    int row0 = rowptr[n], row1 = rowptr[n + 1];
    int deg = row1 - row0;

    const float* qn = q + ((size_t)n) * NR * DD;
    float m = -__builtin_inff(), z = 0.f, acc = 0.f;

    int p = (deg > 0) ? epack[row0] : 0;
    for (int i = 0; i < deg; ++i) {
        int s = p & 0xffff;
        int r = p >> 16;
        float qv  = qn[r * DD + lane];
        float hsv = hbuf[(size_t)s * OSTRIDE + off_in + lane];
        if (i + 1 < deg) p = epack[row0 + i + 1];
        float v = hsv * qv;
        #pragma unroll
        for (int o = 32; o; o >>= 1) v += __shfl_xor(v, o, 64);
        float mn = fmaxf(m, v);
        float sc = __expf(m - mn);
        float w  = __expf(v - mn);
        z   = z * sc + w;
        acc = acc * sc + w * hsv;
        m = mn;
    }
    h_nb[(size_t)n * DD + lane] = (deg > 0) ? acc / z : 0.f;
}

// ---------- epilogue GEMM ----------
__global__ __launch_bounds__(256) void k_out2(const float* __restrict__ h_nb,
                                              const float* __restrict__ ra,
                                              const float* __restrict__ rb,
                                              float* __restrict__ out,
                                              int off_in, int off_out) {
    __shared__ __align__(16) float v1s[64][68];
    __shared__ __align__(16) float v2s[64][68];
    __shared__ __align__(16) float ws[2][64][64];
    int t = threadIdx.x;
    int n0 = blockIdx.x * 64;

    for (int i = t; i < 1024; i += 256) {
        int ni = i >> 4, c4 = (i & 15) * 4;
        int n = n0 + ni;
        float4 hv = make_float4(0.f, 0.f, 0.f, 0.f);
        float4 nb = make_float4(0.f, 0.f, 0.f, 0.f);
        if (n < NN) {
            hv = *(const float4*)&out[(size_t)n * OSTRIDE + off_in + c4];
            nb = *(const float4*)&h_nb[(size_t)n * DD + c4];
        }
        v1s[c4 + 0][ni] = hv.x + nb.x;  v2s[c4 + 0][ni] = hv.x * nb.x;
        v1s[c4 + 1][ni] = hv.y + nb.y;  v2s[c4 + 1][ni] = hv.y * nb.y;
        v1s[c4 + 2][ni] = hv.z + nb.z;  v2s[c4 + 2][ni] = hv.z * nb.z;
        v1s[c4 + 3][ni] = hv.w + nb.w;  v2s[c4 + 3][ni] = hv.w * nb.w;
    }
    for (int i = t; i < 2048; i += 256) {
        const float* base = (i < 1024) ? ra : rb;
        int rem = i & 1023;
        float4 v = *(const float4*)&base[rem * 4];
        int k = rem >> 4, c4 = (rem & 15) * 4;
        *(float4*)&ws[i >> 10][k][c4] = v;
    }
    __syncthreads();

    int nd0 = (t >> 4) * 4;
    int c0  = (t & 15) * 4;
    float a1[4][4] = {}, a2[4][4] = {};
    #pragma unroll 8
    for (int k = 0; k < 64; ++k) {
        float4 h1 = *(const float4*)&v1s[k][nd0];
        float4 h2 = *(const float4*)&v2s[k][nd0];
        float4 wa = *(const float4*)&ws[0][k][c0];
        float4 wb = *(const float4*)&ws[1][k][c0];
        float x1[4] = {h1.x, h1.y, h1.z, h1.w};
        float x2[4] = {h2.x, h2.y, h2.z, h2.w};
        #pragma unroll
        for (int i = 0; i < 4; ++i) {
            a1[i][0] += x1[i] * wa.x; a1[i][1] += x1[i] * wa.y;
            a1[i][2] += x1[i] * wa.z; a1[i][3] += x1[i] * wa.w;
            a2[i][0] += x2[i] * wb.x; a2[i][1] += x2[i] * wb.y;
            a2[i][2] += x2[i] * wb.z; a2[i][3] += x2[i] * wb.w;
        }
    }
    #pragma unroll
    for (int i = 0; i < 4; ++i) {
        int n = n0 + nd0 + i;
        if (n >= NN) continue;
        float4 o;
        float* po = (float*)&o;
        #pragma unroll
        for (int j = 0; j < 4; ++j) {
            float u1 = a1[i][j], u2 = a2[i][j];
            u1 = u1 > 0.f ? u1 : 0.01f * u1;
            u2 = u2 > 0.f ? u2 : 0.01f * u2;
            po[j] = u1 + u2;
        }
        *(float4*)&out[(size_t)n * OSTRIDE + off_out + c0] = o;
    }
}

// ---------- launch ----------
extern "C" void kernel_launch(void* const* d_in, const int* in_sizes, int n_in,
                              void* d_out, int out_size, void* d_ws, size_t ws_size,
                              hipStream_t stream) {
    const int*   node_ids = (const int*)d_in[0];
    const int*   rel_ids  = (const int*)d_in[1];
    const int*   src      = (const int*)d_in[2];
    const int*   dst      = (const int*)d_in[3];
    const float* ent      = (const float*)d_in[4];
    const float* relE     = (const float*)d_in[5];
    const float* W[2]  = {(const float*)d_in[6], (const float*)d_in[7]};
    const float* ra[2] = {(const float*)d_in[8], (const float*)d_in[10]};
    const float* rb[2] = {(const float*)d_in[9], (const float*)d_in[11]};
    float* out = (float*)d_out;

    const size_t q_bytes      = (size_t)NN * NR * DD * sizeof(float);  // 204.8 MB
    const size_t hnb_bytes    = (size_t)NN * DD * sizeof(float);       // 12.8 MB
    const size_t epack_bytes  = (size_t)NE * sizeof(int);              // 3.2 MB
    const size_t rowptr_bytes = (size_t)(NN + 1) * sizeof(int);
    const size_t cnt_bytes    = (size_t)NN * sizeof(int);
    const size_t mask_bytes   = (size_t)NN * sizeof(int);

    char* p = (char*)d_ws;
    float* q      = (float*)p; p += q_bytes;
    float* h_nb   = (float*)p; p += hnb_bytes;
    int*   epack  = (int*)p;   p += epack_bytes;
    int*   rowptr = (int*)p;   p += rowptr_bytes;
    int*   cnt    = (int*)p;   p += cnt_bytes;
    size_t used = (size_t)(p - (char*)d_ws);
    int* relmask = (used + mask_bytes <= ws_size) ? (int*)p : nullptr;

    // ---- CSR build (shared by both layers) ----
    hipMemsetAsync(cnt, 0, cnt_bytes, stream);
    if (relmask) hipMemsetAsync(relmask, 0, mask_bytes, stream);
    k_deg <<<1024, 256, 0, stream>>>(dst, rel_ids, cnt, relmask);
    k_scan<<<1, 1024, 0, stream>>>(cnt, rowptr);
    k_fill<<<1024, 256, 0, stream>>>(dst, src, rel_ids, cnt, epack);

    // ---- h0 ----
    k_copy_h0<<<(NN * DD + 255) / 256, 256, 0, stream>>>(node_ids, ent, out);

    dim3 tq_grid((NN + 63) / 64, NR);
    for (int L = 0; L < 2; ++L) {
        int off_in = L * DD;
        int off_out = (L + 1) * DD;

        k_transq2<<<tq_grid, 512, 0, stream>>>(out, off_in, W[L], relE,
                                               relmask, q);
        k_fused2<<<(NN + 3) / 4, 256, 0, stream>>>(q, out, off_in,
                                                   rowptr, epack, h_nb);
        k_out2  <<<(NN + 63) / 64, 256, 0, stream>>>(h_nb, ra[L], rb[L], out,
                                                     off_in, off_out);
    }
}

// Round 6
// 694.935 us; speedup vs baseline: 1.4177x; 1.2579x over previous
//
#include <hip/hip_runtime.h>
#include <hip/hip_bf16.h>
#include <math.h>

#define NN 50000
#define NE 800000
#define NR 16
#define DD 64
#define OSTRIDE 192   // 3*D concat output stride

typedef __attribute__((ext_vector_type(8))) short bf16x8;
typedef __attribute__((ext_vector_type(4))) float f32x4;

__device__ inline float tanh_fast(float x) {
    return 1.f - 2.f / (__expf(2.f * x) + 1.f);
}
__device__ inline unsigned short f2bf(float f) {   // RNE f32 -> bf16
    unsigned u = __float_as_uint(f);
    return (unsigned short)((u + 0x7fffu + ((u >> 16) & 1u)) >> 16);
}
__device__ inline float bf2f(unsigned short s) {
    return __uint_as_float((unsigned)s << 16);
}

// ---------- CSR build + per-node relation mask ----------
__global__ void k_deg(const int* __restrict__ dst, const int* __restrict__ rel,
                      int* __restrict__ cnt, int* __restrict__ relmask) {
    for (int e = blockIdx.x * blockDim.x + threadIdx.x; e < NE;
         e += gridDim.x * blockDim.x) {
        int d = dst[e];
        atomicAdd(&cnt[d], 1);
        if (relmask) atomicOr(&relmask[d], 1 << rel[e]);
    }
}

__global__ __launch_bounds__(1024) void k_scan(int* __restrict__ cnt,
                                               int* __restrict__ rowptr) {
    __shared__ int part[1024];
    int t = threadIdx.x;
    const int CH = (NN + 1023) / 1024;
    int lo = t * CH, hi = lo + CH > NN ? NN : lo + CH;
    int s = 0;
    for (int i = lo; i < hi; ++i) s += cnt[i];
    part[t] = s;
    __syncthreads();
    for (int o = 1; o < 1024; o <<= 1) {
        int v = (t >= o) ? part[t - o] : 0;
        __syncthreads();
        part[t] += v;
        __syncthreads();
    }
    int run = (t == 0) ? 0 : part[t - 1];
    for (int i = lo; i < hi; ++i) {
        int d = cnt[i];
        rowptr[i] = run;
        cnt[i] = run;        // fill cursor
        run += d;
    }
    if (t == 1023) rowptr[NN] = run;
}

// epack[pos] = src | (rel<<16)
__global__ void k_fill(const int* __restrict__ dst, const int* __restrict__ src,
                       const int* __restrict__ rel, int* __restrict__ cursor,
                       int* __restrict__ epack) {
    for (int e = blockIdx.x * blockDim.x + threadIdx.x; e < NE;
         e += gridDim.x * blockDim.x) {
        int pos = atomicAdd(&cursor[dst[e]], 1);
        epack[pos] = src[e] | (rel[e] << 16);
    }
}

// ---------- h0 gather (f32 out slice + bf16 shadow) ----------
__global__ void k_copy_h0(const int* __restrict__ node_ids,
                          const float* __restrict__ ent,
                          float* __restrict__ out,
                          unsigned short* __restrict__ hbf) {
    int i = blockIdx.x * blockDim.x + threadIdx.x;
    if (i >= NN * DD) return;
    int n = i >> 6, d = i & 63;
    float v = ent[(size_t)node_ids[n] * DD + d];
    out[(size_t)n * OSTRIDE + d] = v;
    hbf[(size_t)n * DD + d] = f2bf(v);
}

// ---------- W -> bf16 tables: wbf[r][d][E], wtbf[r][E][d] ----------
__global__ void k_wprep(const float* __restrict__ W, unsigned short* __restrict__ wbf,
                        unsigned short* __restrict__ wtbf) {
    int i = blockIdx.x * blockDim.x + threadIdx.x;   // 16*64*64 = 65536
    if (i >= NR * DD * DD) return;
    int r = i >> 12, rem = i & 4095, d = rem >> 6, E = rem & 63;
    unsigned short v = f2bf(W[i]);
    wbf[i] = v;
    wtbf[(r << 12) | (E << 6) | d] = v;
}

// ---------- q[n,r,:] = W_r @ tanh(h[n,:]@W_r + e_r), bf16, MFMA ----------
// grid (NR, tiles) r-fastest; 256 thr = 4 waves, wave w owns 16-node m-tile.
__global__ __launch_bounds__(256) void k_transq3(const unsigned short* __restrict__ hbf,
                                                 const unsigned short* __restrict__ wbf,
                                                 const unsigned short* __restrict__ wtbf,
                                                 const float* __restrict__ relE,
                                                 const int* __restrict__ relmask,
                                                 unsigned short* __restrict__ qbf) {
    __shared__ unsigned short u_lds[64][72];   // U[m][E] bf16, pad 72 (144B rows)
    int r  = blockIdx.x;
    int n0 = blockIdx.y * 64;
    int t  = threadIdx.x;
    int w  = t >> 6, l = t & 63;
    int l15 = l & 15, lg = l >> 4;

    // ---- GEMM1: T[m,E] = h[m,:] @ W_r   (A = hbf rows, B = wtbf rows = B^T) ----
    int arow = n0 + w * 16 + l15;
    if (arow >= NN) arow = NN - 1;                 // clamp tail (stores masked)
    const unsigned short* ap = hbf + (size_t)arow * DD + lg * 8;
    bf16x8 a0 = *(const bf16x8*)ap;
    bf16x8 a1 = *(const bf16x8*)(ap + 32);

    f32x4 acc[4];
    #pragma unroll
    for (int nt = 0; nt < 4; ++nt) acc[nt] = (f32x4){0.f, 0.f, 0.f, 0.f};

    const unsigned short* wtr = wtbf + (r << 12);
    #pragma unroll
    for (int nt = 0; nt < 4; ++nt) {
        const unsigned short* bp = wtr + (nt * 16 + l15) * DD + lg * 8;
        bf16x8 b0 = *(const bf16x8*)bp;
        bf16x8 b1 = *(const bf16x8*)(bp + 32);
        acc[nt] = __builtin_amdgcn_mfma_f32_16x16x32_bf16(a0, b0, acc[nt], 0, 0, 0);
        acc[nt] = __builtin_amdgcn_mfma_f32_16x16x32_bf16(a1, b1, acc[nt], 0, 0, 0);
    }

    // ---- U = tanh(T + e_r) -> u_lds ----
    #pragma unroll
    for (int nt = 0; nt < 4; ++nt) {
        int E = nt * 16 + l15;
        float er = relE[r * DD + E];
        #pragma unroll
        for (int reg = 0; reg < 4; ++reg) {
            int m = w * 16 + lg * 4 + reg;
            u_lds[m][E] = f2bf(tanh_fast(acc[nt][reg] + er));
        }
    }
    __syncthreads();

    // ---- GEMM2: Q[m,d] = U[m,:] @ W_r^T  (A = u_lds rows, B = wbf rows = B^T) ----
    const unsigned short* up = &u_lds[w * 16 + l15][lg * 8];
    bf16x8 u0 = *(const bf16x8*)up;
    bf16x8 u1 = *(const bf16x8*)(up + 32);

    f32x4 q4[4];
    #pragma unroll
    for (int nt = 0; nt < 4; ++nt) q4[nt] = (f32x4){0.f, 0.f, 0.f, 0.f};

    const unsigned short* wr = wbf + (r << 12);
    #pragma unroll
    for (int nt = 0; nt < 4; ++nt) {
        const unsigned short* bp = wr + (nt * 16 + l15) * DD + lg * 8;
        bf16x8 b0 = *(const bf16x8*)bp;
        bf16x8 b1 = *(const bf16x8*)(bp + 32);
        q4[nt] = __builtin_amdgcn_mfma_f32_16x16x32_bf16(u0, b0, q4[nt], 0, 0, 0);
        q4[nt] = __builtin_amdgcn_mfma_f32_16x16x32_bf16(u1, b1, q4[nt], 0, 0, 0);
    }

    // ---- masked bf16 store: qbf[node][r][d] ----
    #pragma unroll
    for (int reg = 0; reg < 4; ++reg) {
        int m = w * 16 + lg * 4 + reg;
        int node = n0 + m;
        if (node < NN) {
            int msk = relmask ? relmask[node] : 0xffff;
            if ((msk >> r) & 1) {
                unsigned short* qp = qbf + ((size_t)node * NR + r) * DD + l15;
                #pragma unroll
                for (int nt = 0; nt < 4; ++nt)
                    qp[nt * 16] = f2bf(q4[nt][reg]);
            }
        }
    }
}

// ---------- fused attention + softmax + aggregate (one wave per dst node) ----------
__global__ __launch_bounds__(256) void k_fused2(const unsigned short* __restrict__ qbf,
                                                const float* __restrict__ hbuf, int off_in,
                                                const int* __restrict__ rowptr,
                                                const int* __restrict__ epack,
                                                float* __restrict__ h_nb) {
    int n = blockIdx.x * 4 + (threadIdx.x >> 6);
    if (n >= NN) return;
    int lane = threadIdx.x & 63;
    int row0 = rowptr[n], row1 = rowptr[n + 1];
    int deg = row1 - row0;

    const unsigned short* qn = qbf + (size_t)n * NR * DD;
    float m = -__builtin_inff(), z = 0.f, acc = 0.f;

    int p = (deg > 0) ? epack[row0] : 0;
    for (int i = 0; i < deg; ++i) {
        int s = p & 0xffff;
        int r = p >> 16;
        float qv  = bf2f(qn[r * DD + lane]);
        float hsv = hbuf[(size_t)s * OSTRIDE + off_in + lane];
        if (i + 1 < deg) p = epack[row0 + i + 1];
        float v = hsv * qv;
        #pragma unroll
        for (int o = 32; o; o >>= 1) v += __shfl_xor(v, o, 64);
        float mn = fmaxf(m, v);
        float sc = __expf(m - mn);
        float w  = __expf(v - mn);
        z   = z * sc + w;
        acc = acc * sc + w * hsv;
        m = mn;
    }
    h_nb[(size_t)n * DD + lane] = (deg > 0) ? acc / z : 0.f;
}

// ---------- epilogue GEMM (f32) + bf16 shadow of new h ----------
__global__ __launch_bounds__(256) void k_out2(const float* __restrict__ h_nb,
                                              const float* __restrict__ ra,
                                              const float* __restrict__ rb,
                                              float* __restrict__ out,
                                              int off_in, int off_out,
                                              unsigned short* __restrict__ hbf) {
    __shared__ __align__(16) float v1s[64][68];
    __shared__ __align__(16) float v2s[64][68];
    __shared__ __align__(16) float ws[2][64][64];
    int t = threadIdx.x;
    int n0 = blockIdx.x * 64;

    for (int i = t; i < 1024; i += 256) {
        int ni = i >> 4, c4 = (i & 15) * 4;
        int n = n0 + ni;
        float4 hv = make_float4(0.f, 0.f, 0.f, 0.f);
        float4 nb = make_float4(0.f, 0.f, 0.f, 0.f);
        if (n < NN) {
            hv = *(const float4*)&out[(size_t)n * OSTRIDE + off_in + c4];
            nb = *(const float4*)&h_nb[(size_t)n * DD + c4];
        }
        v1s[c4 + 0][ni] = hv.x + nb.x;  v2s[c4 + 0][ni] = hv.x * nb.x;
        v1s[c4 + 1][ni] = hv.y + nb.y;  v2s[c4 + 1][ni] = hv.y * nb.y;
        v1s[c4 + 2][ni] = hv.z + nb.z;  v2s[c4 + 2][ni] = hv.z * nb.z;
        v1s[c4 + 3][ni] = hv.w + nb.w;  v2s[c4 + 3][ni] = hv.w * nb.w;
    }
    for (int i = t; i < 2048; i += 256) {
        const float* base = (i < 1024) ? ra : rb;
        int rem = i & 1023;
        float4 v = *(const float4*)&base[rem * 4];
        int k = rem >> 4, c4 = (rem & 15) * 4;
        *(float4*)&ws[i >> 10][k][c4] = v;
    }
    __syncthreads();

    int nd0 = (t >> 4) * 4;
    int c0  = (t & 15) * 4;
    float a1[4][4] = {}, a2[4][4] = {};
    #pragma unroll 8
    for (int k = 0; k < 64; ++k) {
        float4 h1 = *(const float4*)&v1s[k][nd0];
        float4 h2 = *(const float4*)&v2s[k][nd0];
        float4 wa = *(const float4*)&ws[0][k][c0];
        float4 wb = *(const float4*)&ws[1][k][c0];
        float x1[4] = {h1.x, h1.y, h1.z, h1.w};
        float x2[4] = {h2.x, h2.y, h2.z, h2.w};
        #pragma unroll
        for (int i = 0; i < 4; ++i) {
            a1[i][0] += x1[i] * wa.x; a1[i][1] += x1[i] * wa.y;
            a1[i][2] += x1[i] * wa.z; a1[i][3] += x1[i] * wa.w;
            a2[i][0] += x2[i] * wb.x; a2[i][1] += x2[i] * wb.y;
            a2[i][2] += x2[i] * wb.z; a2[i][3] += x2[i] * wb.w;
        }
    }
    #pragma unroll
    for (int i = 0; i < 4; ++i) {
        int n = n0 + nd0 + i;
        if (n >= NN) continue;
        float4 o;
        float* po = (float*)&o;
        #pragma unroll
        for (int j = 0; j < 4; ++j) {
            float u1 = a1[i][j], u2 = a2[i][j];
            u1 = u1 > 0.f ? u1 : 0.01f * u1;
            u2 = u2 > 0.f ? u2 : 0.01f * u2;
            po[j] = u1 + u2;
        }
        *(float4*)&out[(size_t)n * OSTRIDE + off_out + c0] = o;
        hbf[(size_t)n * DD + c0 + 0] = f2bf(o.x);
        hbf[(size_t)n * DD + c0 + 1] = f2bf(o.y);
        hbf[(size_t)n * DD + c0 + 2] = f2bf(o.z);
        hbf[(size_t)n * DD + c0 + 3] = f2bf(o.w);
    }
}

// ---------- launch ----------
extern "C" void kernel_launch(void* const* d_in, const int* in_sizes, int n_in,
                              void* d_out, int out_size, void* d_ws, size_t ws_size,
                              hipStream_t stream) {
    const int*   node_ids = (const int*)d_in[0];
    const int*   rel_ids  = (const int*)d_in[1];
    const int*   src      = (const int*)d_in[2];
    const int*   dst      = (const int*)d_in[3];
    const float* ent      = (const float*)d_in[4];
    const float* relE     = (const float*)d_in[5];
    const float* W[2]  = {(const float*)d_in[6], (const float*)d_in[7]};
    const float* ra[2] = {(const float*)d_in[8], (const float*)d_in[10]};
    const float* rb[2] = {(const float*)d_in[9], (const float*)d_in[11]};
    float* out = (float*)d_out;

    const size_t hnb_bytes    = (size_t)NN * DD * sizeof(float);            // 12.8 MB
    const size_t qbf_bytes    = (size_t)NN * NR * DD * sizeof(short);       // 102.4 MB
    const size_t hbf_bytes    = (size_t)NN * DD * sizeof(short);            // 6.4 MB
    const size_t wbf_bytes    = (size_t)NR * DD * DD * sizeof(short);       // 128 KB
    const size_t epack_bytes  = (size_t)NE * sizeof(int);                   // 3.2 MB
    const size_t rowptr_bytes = (size_t)(NN + 1) * sizeof(int);
    const size_t cnt_bytes    = (size_t)NN * sizeof(int);
    const size_t mask_bytes   = (size_t)NN * sizeof(int);

    char* p = (char*)d_ws;
    float*          h_nb   = (float*)p;          p += hnb_bytes;
    unsigned short* qbf    = (unsigned short*)p; p += qbf_bytes;
    unsigned short* hbf    = (unsigned short*)p; p += hbf_bytes;
    unsigned short* wbf    = (unsigned short*)p; p += wbf_bytes;
    unsigned short* wtbf   = (unsigned short*)p; p += wbf_bytes;
    int*            epack  = (int*)p;            p += epack_bytes;
    int*            rowptr = (int*)p;            p += rowptr_bytes;
    int*            cnt    = (int*)p;            p += cnt_bytes;
    size_t used = (size_t)(p - (char*)d_ws);
    int* relmask = (used + mask_bytes <= ws_size) ? (int*)p : nullptr;

    // ---- CSR build (shared by both layers) ----
    hipMemsetAsync(cnt, 0, cnt_bytes, stream);
    if (relmask) hipMemsetAsync(relmask, 0, mask_bytes, stream);
    k_deg <<<1024, 256, 0, stream>>>(dst, rel_ids, cnt, relmask);
    k_scan<<<1, 1024, 0, stream>>>(cnt, rowptr);
    k_fill<<<1024, 256, 0, stream>>>(dst, src, rel_ids, cnt, epack);

    // ---- h0 ----
    k_copy_h0<<<(NN * DD + 255) / 256, 256, 0, stream>>>(node_ids, ent, out, hbf);

    dim3 tq_grid(NR, (NN + 63) / 64);
    for (int L = 0; L < 2; ++L) {
        int off_in = L * DD;
        int off_out = (L + 1) * DD;

        k_wprep <<<(NR * DD * DD + 255) / 256, 256, 0, stream>>>(W[L], wbf, wtbf);
        k_transq3<<<tq_grid, 256, 0, stream>>>(hbf, wbf, wtbf, relE, relmask, qbf);
        k_fused2<<<(NN + 3) / 4, 256, 0, stream>>>(qbf, out, off_in,
                                                   rowptr, epack, h_nb);
        k_out2  <<<(NN + 63) / 64, 256, 0, stream>>>(h_nb, ra[L], rb[L], out,
                                                     off_in, off_out, hbf);
    }
}

// Round 7
// 631.273 us; speedup vs baseline: 1.5607x; 1.1008x over previous
//
#include <hip/hip_runtime.h>
#include <hip/hip_bf16.h>
#include <math.h>

#define NN 50000
#define NE 800000
#define NR 16
#define DD 64
#define OSTRIDE 192   // 3*D concat output stride

typedef __attribute__((ext_vector_type(8))) short bf16x8;
typedef __attribute__((ext_vector_type(4))) float f32x4;

__device__ inline float tanh_fast(float x) {
    return 1.f - 2.f / (__expf(2.f * x) + 1.f);
}
__device__ inline unsigned short f2bf(float f) {   // RNE f32 -> bf16
    unsigned u = __float_as_uint(f);
    return (unsigned short)((u + 0x7fffu + ((u >> 16) & 1u)) >> 16);
}
__device__ inline float bf2f(unsigned short s) {
    return __uint_as_float((unsigned)s << 16);
}

// ---------- CSR build + per-node relation mask ----------
__global__ void k_deg(const int* __restrict__ dst, const int* __restrict__ rel,
                      int* __restrict__ cnt, int* __restrict__ relmask) {
    for (int e = blockIdx.x * blockDim.x + threadIdx.x; e < NE;
         e += gridDim.x * blockDim.x) {
        int d = dst[e];
        atomicAdd(&cnt[d], 1);
        if (relmask) atomicOr(&relmask[d], 1 << rel[e]);
    }
}

__global__ __launch_bounds__(1024) void k_scan(int* __restrict__ cnt,
                                               int* __restrict__ rowptr) {
    __shared__ int part[1024];
    int t = threadIdx.x;
    const int CH = (NN + 1023) / 1024;
    int lo = t * CH, hi = lo + CH > NN ? NN : lo + CH;
    int s = 0;
    for (int i = lo; i < hi; ++i) s += cnt[i];
    part[t] = s;
    __syncthreads();
    for (int o = 1; o < 1024; o <<= 1) {
        int v = (t >= o) ? part[t - o] : 0;
        __syncthreads();
        part[t] += v;
        __syncthreads();
    }
    int run = (t == 0) ? 0 : part[t - 1];
    for (int i = lo; i < hi; ++i) {
        int d = cnt[i];
        rowptr[i] = run;
        cnt[i] = run;        // fill cursor
        run += d;
    }
    if (t == 1023) rowptr[NN] = run;
}

// epack[pos] = src | (rel<<16)
__global__ void k_fill(const int* __restrict__ dst, const int* __restrict__ src,
                       const int* __restrict__ rel, int* __restrict__ cursor,
                       int* __restrict__ epack) {
    for (int e = blockIdx.x * blockDim.x + threadIdx.x; e < NE;
         e += gridDim.x * blockDim.x) {
        int pos = atomicAdd(&cursor[dst[e]], 1);
        epack[pos] = src[e] | (rel[e] << 16);
    }
}

// ---------- h0 gather (f32 out slice + bf16 shadow) ----------
__global__ void k_copy_h0(const int* __restrict__ node_ids,
                          const float* __restrict__ ent,
                          float* __restrict__ out,
                          unsigned short* __restrict__ hbf) {
    int i = blockIdx.x * blockDim.x + threadIdx.x;
    if (i >= NN * DD) return;
    int n = i >> 6, d = i & 63;
    float v = ent[(size_t)node_ids[n] * DD + d];
    out[(size_t)n * OSTRIDE + d] = v;
    hbf[(size_t)n * DD + d] = f2bf(v);
}

// ---------- W -> bf16 tables: wbf[r][d][E], wtbf[r][E][d] ----------
__global__ void k_wprep(const float* __restrict__ W, unsigned short* __restrict__ wbf,
                        unsigned short* __restrict__ wtbf) {
    int i = blockIdx.x * blockDim.x + threadIdx.x;   // 16*64*64 = 65536
    if (i >= NR * DD * DD) return;
    int r = i >> 12, rem = i & 4095, d = rem >> 6, E = rem & 63;
    unsigned short v = f2bf(W[i]);
    wbf[i] = v;
    wtbf[(r << 12) | (E << 6) | d] = v;
}

// ---------- q[n,r,:] = W_r @ tanh(h[n,:]@W_r + e_r), bf16, MFMA, barrier-free ----------
// grid (NR, tiles); 256 thr = 4 waves; each wave owns a 16-node tile and a
// PRIVATE u_lds slice -> cross-lane transpose stays inside the wave, so a
// wave-level s_waitcnt lgkmcnt(0) replaces __syncthreads (no block barriers).
__global__ __launch_bounds__(256) void k_transq3(const unsigned short* __restrict__ hbf,
                                                 const unsigned short* __restrict__ wbf,
                                                 const unsigned short* __restrict__ wtbf,
                                                 const float* __restrict__ relE,
                                                 const int* __restrict__ relmask,
                                                 unsigned short* __restrict__ qbf) {
    __shared__ unsigned short u_lds[4][16][72];   // per-wave slice, 144B rows (16B-aligned)
    int r  = blockIdx.x;
    int n0 = blockIdx.y * 64;
    int t  = threadIdx.x;
    int w  = t >> 6, l = t & 63;
    int l15 = l & 15, lg = l >> 4;

    // ---- GEMM1: T[m,E] = h[m,:] @ W_r   (A = hbf rows, B = wtbf rows = B^T) ----
    int arow = n0 + w * 16 + l15;
    if (arow >= NN) arow = NN - 1;                 // clamp tail (stores masked)
    const unsigned short* ap = hbf + (size_t)arow * DD + lg * 8;
    bf16x8 a0 = *(const bf16x8*)ap;
    bf16x8 a1 = *(const bf16x8*)(ap + 32);

    f32x4 acc[4];
    #pragma unroll
    for (int nt = 0; nt < 4; ++nt) acc[nt] = (f32x4){0.f, 0.f, 0.f, 0.f};

    const unsigned short* wtr = wtbf + (r << 12);
    #pragma unroll
    for (int nt = 0; nt < 4; ++nt) {
        const unsigned short* bp = wtr + (nt * 16 + l15) * DD + lg * 8;
        bf16x8 b0 = *(const bf16x8*)bp;
        bf16x8 b1 = *(const bf16x8*)(bp + 32);
        acc[nt] = __builtin_amdgcn_mfma_f32_16x16x32_bf16(a0, b0, acc[nt], 0, 0, 0);
        acc[nt] = __builtin_amdgcn_mfma_f32_16x16x32_bf16(a1, b1, acc[nt], 0, 0, 0);
    }

    // ---- U = tanh(T + e_r) -> wave-private u_lds ----
    #pragma unroll
    for (int nt = 0; nt < 4; ++nt) {
        int E = nt * 16 + l15;
        float er = relE[r * DD + E];
        #pragma unroll
        for (int reg = 0; reg < 4; ++reg)
            u_lds[w][lg * 4 + reg][E] = f2bf(tanh_fast(acc[nt][reg] + er));
    }
    // wave-local LDS writes -> reads: waiting on this wave's LDS ops suffices
    asm volatile("s_waitcnt lgkmcnt(0)" ::: "memory");

    // ---- GEMM2: Q[m,d] = U[m,:] @ W_r^T  (A = u_lds rows, B = wbf rows = B^T) ----
    const unsigned short* up = &u_lds[w][l15][lg * 8];
    bf16x8 u0 = *(const bf16x8*)up;
    bf16x8 u1 = *(const bf16x8*)(up + 32);

    f32x4 q4[4];
    #pragma unroll
    for (int nt = 0; nt < 4; ++nt) q4[nt] = (f32x4){0.f, 0.f, 0.f, 0.f};

    const unsigned short* wr = wbf + (r << 12);
    #pragma unroll
    for (int nt = 0; nt < 4; ++nt) {
        const unsigned short* bp = wr + (nt * 16 + l15) * DD + lg * 8;
        bf16x8 b0 = *(const bf16x8*)bp;
        bf16x8 b1 = *(const bf16x8*)(bp + 32);
        q4[nt] = __builtin_amdgcn_mfma_f32_16x16x32_bf16(u0, b0, q4[nt], 0, 0, 0);
        q4[nt] = __builtin_amdgcn_mfma_f32_16x16x32_bf16(u1, b1, q4[nt], 0, 0, 0);
    }

    // ---- masked bf16 store: qbf[node][r][d] ----
    #pragma unroll
    for (int reg = 0; reg < 4; ++reg) {
        int m = w * 16 + lg * 4 + reg;
        int node = n0 + m;
        if (node < NN) {
            int msk = relmask ? relmask[node] : 0xffff;
            if ((msk >> r) & 1) {
                unsigned short* qp = qbf + ((size_t)node * NR + r) * DD + l15;
                #pragma unroll
                for (int nt = 0; nt < 4; ++nt)
                    qp[nt * 16] = f2bf(q4[nt][reg]);
            }
        }
    }
}

// ---------- fused attention + softmax + aggregate (one wave per dst node) ----------
// Chunk-of-8 edge processing: 8 independent dot-reduces (ILP), one rescale/chunk.
// h_src gathered from bf16 hbf (6.4 MB, L2-resident).
__global__ __launch_bounds__(256) void k_fused3(const unsigned short* __restrict__ qbf,
                                                const unsigned short* __restrict__ hbf,
                                                const int* __restrict__ rowptr,
                                                const int* __restrict__ epack,
                                                float* __restrict__ h_nb) {
    int n = blockIdx.x * 4 + (threadIdx.x >> 6);
    if (n >= NN) return;
    int lane = threadIdx.x & 63;
    int row0 = rowptr[n], deg = rowptr[n + 1] - row0;

    const unsigned short* qn = qbf + (size_t)n * NR * DD;
    float m = -__builtin_inff(), z = 0.f, acc = 0.f;

    int i = 0;
    for (; i + 8 <= deg; i += 8) {
        float v[8], hv[8];
        #pragma unroll
        for (int j = 0; j < 8; ++j) {
            int p = epack[row0 + i + j];
            int s = p & 0xffff, r = p >> 16;
            hv[j] = bf2f(hbf[(size_t)s * DD + lane]);
            v[j]  = hv[j] * bf2f(qn[r * DD + lane]);
        }
        #pragma unroll
        for (int o = 32; o; o >>= 1) {
            #pragma unroll
            for (int j = 0; j < 8; ++j)
                v[j] += __shfl_xor(v[j], o, 64);
        }
        float cm = v[0];
        #pragma unroll
        for (int j = 1; j < 8; ++j) cm = fmaxf(cm, v[j]);
        float mn = fmaxf(m, cm);
        float sc = __expf(m - mn);     // m=-inf first chunk -> 0
        z *= sc;
        acc *= sc;
        #pragma unroll
        for (int j = 0; j < 8; ++j) {
            float wgt = __expf(v[j] - mn);
            z += wgt;
            acc += wgt * hv[j];
        }
        m = mn;
    }
    for (; i < deg; ++i) {
        int p = epack[row0 + i];
        int s = p & 0xffff, r = p >> 16;
        float hsv = bf2f(hbf[(size_t)s * DD + lane]);
        float v = hsv * bf2f(qn[r * DD + lane]);
        #pragma unroll
        for (int o = 32; o; o >>= 1) v += __shfl_xor(v, o, 64);
        float mn = fmaxf(m, v);
        float sc = __expf(m - mn);
        float wgt = __expf(v - mn);
        z   = z * sc + wgt;
        acc = acc * sc + wgt * hsv;
        m = mn;
    }
    h_nb[(size_t)n * DD + lane] = (deg > 0) ? acc / z : 0.f;
}

// ---------- epilogue GEMM (f32) + bf16 shadow of new h ----------
__global__ __launch_bounds__(256) void k_out2(const float* __restrict__ h_nb,
                                              const float* __restrict__ ra,
                                              const float* __restrict__ rb,
                                              float* __restrict__ out,
                                              int off_in, int off_out,
                                              unsigned short* __restrict__ hbf) {
    __shared__ __align__(16) float v1s[64][68];
    __shared__ __align__(16) float v2s[64][68];
    __shared__ __align__(16) float ws[2][64][64];
    int t = threadIdx.x;
    int n0 = blockIdx.x * 64;

    for (int i = t; i < 1024; i += 256) {
        int ni = i >> 4, c4 = (i & 15) * 4;
        int n = n0 + ni;
        float4 hv = make_float4(0.f, 0.f, 0.f, 0.f);
        float4 nb = make_float4(0.f, 0.f, 0.f, 0.f);
        if (n < NN) {
            hv = *(const float4*)&out[(size_t)n * OSTRIDE + off_in + c4];
            nb = *(const float4*)&h_nb[(size_t)n * DD + c4];
        }
        v1s[c4 + 0][ni] = hv.x + nb.x;  v2s[c4 + 0][ni] = hv.x * nb.x;
        v1s[c4 + 1][ni] = hv.y + nb.y;  v2s[c4 + 1][ni] = hv.y * nb.y;
        v1s[c4 + 2][ni] = hv.z + nb.z;  v2s[c4 + 2][ni] = hv.z * nb.z;
        v1s[c4 + 3][ni] = hv.w + nb.w;  v2s[c4 + 3][ni] = hv.w * nb.w;
    }
    for (int i = t; i < 2048; i += 256) {
        const float* base = (i < 1024) ? ra : rb;
        int rem = i & 1023;
        float4 v = *(const float4*)&base[rem * 4];
        int k = rem >> 4, c4 = (rem & 15) * 4;
        *(float4*)&ws[i >> 10][k][c4] = v;
    }
    __syncthreads();

    int nd0 = (t >> 4) * 4;
    int c0  = (t & 15) * 4;
    float a1[4][4] = {}, a2[4][4] = {};
    #pragma unroll 8
    for (int k = 0; k < 64; ++k) {
        float4 h1 = *(const float4*)&v1s[k][nd0];
        float4 h2 = *(const float4*)&v2s[k][nd0];
        float4 wa = *(const float4*)&ws[0][k][c0];
        float4 wb = *(const float4*)&ws[1][k][c0];
        float x1[4] = {h1.x, h1.y, h1.z, h1.w};
        float x2[4] = {h2.x, h2.y, h2.z, h2.w};
        #pragma unroll
        for (int i = 0; i < 4; ++i) {
            a1[i][0] += x1[i] * wa.x; a1[i][1] += x1[i] * wa.y;
            a1[i][2] += x1[i] * wa.z; a1[i][3] += x1[i] * wa.w;
            a2[i][0] += x2[i] * wb.x; a2[i][1] += x2[i] * wb.y;
            a2[i][2] += x2[i] * wb.z; a2[i][3] += x2[i] * wb.w;
        }
    }
    #pragma unroll
    for (int i = 0; i < 4; ++i) {
        int n = n0 + nd0 + i;
        if (n >= NN) continue;
        float4 o;
        float* po = (float*)&o;
        #pragma unroll
        for (int j = 0; j < 4; ++j) {
            float u1 = a1[i][j], u2 = a2[i][j];
            u1 = u1 > 0.f ? u1 : 0.01f * u1;
            u2 = u2 > 0.f ? u2 : 0.01f * u2;
            po[j] = u1 + u2;
        }
        *(float4*)&out[(size_t)n * OSTRIDE + off_out + c0] = o;
        hbf[(size_t)n * DD + c0 + 0] = f2bf(o.x);
        hbf[(size_t)n * DD + c0 + 1] = f2bf(o.y);
        hbf[(size_t)n * DD + c0 + 2] = f2bf(o.z);
        hbf[(size_t)n * DD + c0 + 3] = f2bf(o.w);
    }
}

// ---------- launch ----------
extern "C" void kernel_launch(void* const* d_in, const int* in_sizes, int n_in,
                              void* d_out, int out_size, void* d_ws, size_t ws_size,
                              hipStream_t stream) {
    const int*   node_ids = (const int*)d_in[0];
    const int*   rel_ids  = (const int*)d_in[1];
    const int*   src      = (const int*)d_in[2];
    const int*   dst      = (const int*)d_in[3];
    const float* ent      = (const float*)d_in[4];
    const float* relE     = (const float*)d_in[5];
    const float* W[2]  = {(const float*)d_in[6], (const float*)d_in[7]};
    const float* ra[2] = {(const float*)d_in[8], (const float*)d_in[10]};
    const float* rb[2] = {(const float*)d_in[9], (const float*)d_in[11]};
    float* out = (float*)d_out;

    const size_t hnb_bytes    = (size_t)NN * DD * sizeof(float);            // 12.8 MB
    const size_t qbf_bytes    = (size_t)NN * NR * DD * sizeof(short);       // 102.4 MB
    const size_t hbf_bytes    = (size_t)NN * DD * sizeof(short);            // 6.4 MB
    const size_t wbf_bytes    = (size_t)NR * DD * DD * sizeof(short);       // 128 KB
    const size_t epack_bytes  = (size_t)NE * sizeof(int);                   // 3.2 MB
    const size_t rowptr_bytes = (size_t)(NN + 1) * sizeof(int);
    const size_t cnt_bytes    = (size_t)NN * sizeof(int);
    const size_t mask_bytes   = (size_t)NN * sizeof(int);

    char* p = (char*)d_ws;
    float*          h_nb   = (float*)p;          p += hnb_bytes;
    unsigned short* qbf    = (unsigned short*)p; p += qbf_bytes;
    unsigned short* hbf    = (unsigned short*)p; p += hbf_bytes;
    unsigned short* wbf    = (unsigned short*)p; p += wbf_bytes;
    unsigned short* wtbf   = (unsigned short*)p; p += wbf_bytes;
    int*            epack  = (int*)p;            p += epack_bytes;
    int*            rowptr = (int*)p;            p += rowptr_bytes;
    int*            cnt    = (int*)p;            p += cnt_bytes;
    size_t used = (size_t)(p - (char*)d_ws);
    int* relmask = (used + mask_bytes <= ws_size) ? (int*)p : nullptr;

    // ---- CSR build (shared by both layers) ----
    hipMemsetAsync(cnt, 0, cnt_bytes, stream);
    if (relmask) hipMemsetAsync(relmask, 0, mask_bytes, stream);
    k_deg <<<1024, 256, 0, stream>>>(dst, rel_ids, cnt, relmask);
    k_scan<<<1, 1024, 0, stream>>>(cnt, rowptr);
    k_fill<<<1024, 256, 0, stream>>>(dst, src, rel_ids, cnt, epack);

    // ---- h0 ----
    k_copy_h0<<<(NN * DD + 255) / 256, 256, 0, stream>>>(node_ids, ent, out, hbf);

    dim3 tq_grid(NR, (NN + 63) / 64);
    for (int L = 0; L < 2; ++L) {
        int off_in = L * DD;
        int off_out = (L + 1) * DD;

        k_wprep <<<(NR * DD * DD + 255) / 256, 256, 0, stream>>>(W[L], wbf, wtbf);
        k_transq3<<<tq_grid, 256, 0, stream>>>(hbf, wbf, wtbf, relE, relmask, qbf);
        k_fused3<<<(NN + 3) / 4, 256, 0, stream>>>(qbf, hbf, rowptr, epack, h_nb);
        k_out2  <<<(NN + 63) / 64, 256, 0, stream>>>(h_nb, ra[L], rb[L], out,
                                                     off_in, off_out, hbf);
    }
}

// Round 8
// 560.425 us; speedup vs baseline: 1.7580x; 1.1264x over previous
//
#include <hip/hip_runtime.h>
#include <hip/hip_bf16.h>
#include <math.h>

#define NN 50000
#define NE 800000
#define NR 16
#define DD 64
#define OSTRIDE 192   // 3*D concat output stride

typedef __attribute__((ext_vector_type(8))) short bf16x8;
typedef __attribute__((ext_vector_type(4))) float f32x4;

__device__ inline float tanh_fast(float x) {
    return 1.f - 2.f / (__expf(2.f * x) + 1.f);
}
__device__ inline unsigned short f2bf(float f) {   // RNE f32 -> bf16
    unsigned u = __float_as_uint(f);
    return (unsigned short)((u + 0x7fffu + ((u >> 16) & 1u)) >> 16);
}
__device__ inline float bf2f(unsigned short s) {
    return __uint_as_float((unsigned)s << 16);
}

// ---------- CSR build + per-node relation mask ----------
__global__ void k_deg(const int* __restrict__ dst, const int* __restrict__ rel,
                      int* __restrict__ cnt, int* __restrict__ relmask) {
    for (int e = blockIdx.x * blockDim.x + threadIdx.x; e < NE;
         e += gridDim.x * blockDim.x) {
        int d = dst[e];
        atomicAdd(&cnt[d], 1);
        if (relmask) atomicOr(&relmask[d], 1 << rel[e]);
    }
}

__global__ __launch_bounds__(1024) void k_scan(int* __restrict__ cnt,
                                               int* __restrict__ rowptr) {
    __shared__ int part[1024];
    int t = threadIdx.x;
    const int CH = (NN + 1023) / 1024;
    int lo = t * CH, hi = lo + CH > NN ? NN : lo + CH;
    int s = 0;
    for (int i = lo; i < hi; ++i) s += cnt[i];
    part[t] = s;
    __syncthreads();
    for (int o = 1; o < 1024; o <<= 1) {
        int v = (t >= o) ? part[t - o] : 0;
        __syncthreads();
        part[t] += v;
        __syncthreads();
    }
    int run = (t == 0) ? 0 : part[t - 1];
    for (int i = lo; i < hi; ++i) {
        int d = cnt[i];
        rowptr[i] = run;
        cnt[i] = run;        // fill cursor
        run += d;
    }
    if (t == 1023) rowptr[NN] = run;
}

// epack[pos] = src | (rel<<16)
__global__ void k_fill(const int* __restrict__ dst, const int* __restrict__ src,
                       const int* __restrict__ rel, int* __restrict__ cursor,
                       int* __restrict__ epack) {
    for (int e = blockIdx.x * blockDim.x + threadIdx.x; e < NE;
         e += gridDim.x * blockDim.x) {
        int pos = atomicAdd(&cursor[dst[e]], 1);
        epack[pos] = src[e] | (rel[e] << 16);
    }
}

// ---------- h0 gather (f32 out slice + bf16 shadow) ----------
__global__ void k_copy_h0(const int* __restrict__ node_ids,
                          const float* __restrict__ ent,
                          float* __restrict__ out,
                          unsigned short* __restrict__ hbf) {
    int i = blockIdx.x * blockDim.x + threadIdx.x;
    if (i >= NN * DD) return;
    int n = i >> 6, d = i & 63;
    float v = ent[(size_t)node_ids[n] * DD + d];
    out[(size_t)n * OSTRIDE + d] = v;
    hbf[(size_t)n * DD + d] = f2bf(v);
}

// ---------- W -> bf16 tables: wbf[r][d][E], wtbf[r][E][d] ----------
__global__ void k_wprep(const float* __restrict__ W, unsigned short* __restrict__ wbf,
                        unsigned short* __restrict__ wtbf) {
    int i = blockIdx.x * blockDim.x + threadIdx.x;   // 16*64*64 = 65536
    if (i >= NR * DD * DD) return;
    int r = i >> 12, rem = i & 4095, d = rem >> 6, E = rem & 63;
    unsigned short v = f2bf(W[i]);
    wbf[i] = v;
    wtbf[(r << 12) | (E << 6) | d] = v;
}

// ---------- q[n,r,:] = W_r @ tanh(h[n,:]@W_r + e_r), bf16 MFMA, 2 tiles/wave ----------
// grid (NR, ceil(NN/128)); 256 thr = 4 waves; wave owns 32 nodes (2 m-tiles),
// sharing B-fragments (W) across both tiles. Barrier-free (wave-private u_lds).
__global__ __launch_bounds__(256) void k_transq4(const unsigned short* __restrict__ hbf,
                                                 const unsigned short* __restrict__ wbf,
                                                 const unsigned short* __restrict__ wtbf,
                                                 const float* __restrict__ relE,
                                                 const int* __restrict__ relmask,
                                                 unsigned short* __restrict__ qbf) {
    __shared__ __align__(16) unsigned short u_lds[4][32][72];  // 144B rows, 16B-aligned
    int r  = blockIdx.x;
    int n0 = blockIdx.y * 128;
    int t  = threadIdx.x;
    int w  = t >> 6, l = t & 63;
    int l15 = l & 15, lg = l >> 4;
    int base = n0 + w * 32;

    // A-fragments for the two 16-node tiles
    int ar0 = base + l15;      if (ar0 >= NN) ar0 = NN - 1;
    int ar1 = base + 16 + l15; if (ar1 >= NN) ar1 = NN - 1;
    const unsigned short* ap0 = hbf + (size_t)ar0 * DD + lg * 8;
    const unsigned short* ap1 = hbf + (size_t)ar1 * DD + lg * 8;
    bf16x8 a00 = *(const bf16x8*)ap0;
    bf16x8 a01 = *(const bf16x8*)(ap0 + 32);
    bf16x8 a10 = *(const bf16x8*)ap1;
    bf16x8 a11 = *(const bf16x8*)(ap1 + 32);

    // ---- GEMM1: T[m,E] = h[m,:] @ W_r   (B = wtbf rows = B^T) ----
    f32x4 acc[2][4];
    #pragma unroll
    for (int ti = 0; ti < 2; ++ti)
        #pragma unroll
        for (int nt = 0; nt < 4; ++nt) acc[ti][nt] = (f32x4){0.f, 0.f, 0.f, 0.f};

    const unsigned short* wtr = wtbf + (r << 12);
    #pragma unroll
    for (int nt = 0; nt < 4; ++nt) {
        const unsigned short* bp = wtr + (nt * 16 + l15) * DD + lg * 8;
        bf16x8 b0 = *(const bf16x8*)bp;
        bf16x8 b1 = *(const bf16x8*)(bp + 32);
        acc[0][nt] = __builtin_amdgcn_mfma_f32_16x16x32_bf16(a00, b0, acc[0][nt], 0, 0, 0);
        acc[0][nt] = __builtin_amdgcn_mfma_f32_16x16x32_bf16(a01, b1, acc[0][nt], 0, 0, 0);
        acc[1][nt] = __builtin_amdgcn_mfma_f32_16x16x32_bf16(a10, b0, acc[1][nt], 0, 0, 0);
        acc[1][nt] = __builtin_amdgcn_mfma_f32_16x16x32_bf16(a11, b1, acc[1][nt], 0, 0, 0);
    }

    // ---- U = tanh(T + e_r) -> wave-private u_lds ----
    #pragma unroll
    for (int nt = 0; nt < 4; ++nt) {
        int E = nt * 16 + l15;
        float er = relE[r * DD + E];
        #pragma unroll
        for (int ti = 0; ti < 2; ++ti)
            #pragma unroll
            for (int reg = 0; reg < 4; ++reg)
                u_lds[w][ti * 16 + lg * 4 + reg][E] = f2bf(tanh_fast(acc[ti][nt][reg] + er));
    }
    asm volatile("s_waitcnt lgkmcnt(0)" ::: "memory");

    // ---- GEMM2: Q[m,d] = U[m,:] @ W_r^T  (B = wbf rows = B^T) ----
    const unsigned short* up0 = &u_lds[w][l15][lg * 8];
    const unsigned short* up1 = &u_lds[w][16 + l15][lg * 8];
    bf16x8 u00 = *(const bf16x8*)up0;
    bf16x8 u01 = *(const bf16x8*)(up0 + 32);
    bf16x8 u10 = *(const bf16x8*)up1;
    bf16x8 u11 = *(const bf16x8*)(up1 + 32);

    f32x4 q4[2][4];
    #pragma unroll
    for (int ti = 0; ti < 2; ++ti)
        #pragma unroll
        for (int nt = 0; nt < 4; ++nt) q4[ti][nt] = (f32x4){0.f, 0.f, 0.f, 0.f};

    const unsigned short* wr = wbf + (r << 12);
    #pragma unroll
    for (int nt = 0; nt < 4; ++nt) {
        const unsigned short* bp = wr + (nt * 16 + l15) * DD + lg * 8;
        bf16x8 b0 = *(const bf16x8*)bp;
        bf16x8 b1 = *(const bf16x8*)(bp + 32);
        q4[0][nt] = __builtin_amdgcn_mfma_f32_16x16x32_bf16(u00, b0, q4[0][nt], 0, 0, 0);
        q4[0][nt] = __builtin_amdgcn_mfma_f32_16x16x32_bf16(u01, b1, q4[0][nt], 0, 0, 0);
        q4[1][nt] = __builtin_amdgcn_mfma_f32_16x16x32_bf16(u10, b0, q4[1][nt], 0, 0, 0);
        q4[1][nt] = __builtin_amdgcn_mfma_f32_16x16x32_bf16(u11, b1, q4[1][nt], 0, 0, 0);
    }

    // ---- masked bf16 store: qbf[node][r][d] ----
    #pragma unroll
    for (int ti = 0; ti < 2; ++ti) {
        #pragma unroll
        for (int reg = 0; reg < 4; ++reg) {
            int node = base + ti * 16 + lg * 4 + reg;
            if (node < NN) {
                int msk = relmask ? relmask[node] : 0xffff;
                if ((msk >> r) & 1) {
                    unsigned short* qp = qbf + ((size_t)node * NR + r) * DD + l15;
                    #pragma unroll
                    for (int nt = 0; nt < 4; ++nt)
                        qp[nt * 16] = f2bf(q4[ti][nt][reg]);
                }
            }
        }
    }
}

// ---------- fused attention + softmax + aggregate (one wave per dst node) ----------
// Node's q[16][64] staged in LDS (coalesced); interleaved 8-value reduce.
__global__ __launch_bounds__(256) void k_fused4(const unsigned short* __restrict__ qbf,
                                                const unsigned short* __restrict__ hbf,
                                                const int* __restrict__ rowptr,
                                                const int* __restrict__ epack,
                                                float* __restrict__ h_nb) {
    __shared__ __align__(16) unsigned short q_lds[4][1024];   // per-wave 2KB
    int wv = threadIdx.x >> 6;
    int n = blockIdx.x * 4 + wv;
    if (n >= NN) return;
    int lane = threadIdx.x & 63;

    // stage this node's 16 q rows (contiguous 2KB) into LDS
    {
        const uint4* s4 = (const uint4*)(qbf + (size_t)n * NR * DD);
        uint4* d4 = (uint4*)q_lds[wv];
        d4[lane]      = s4[lane];
        d4[lane + 64] = s4[lane + 64];
    }
    asm volatile("s_waitcnt vmcnt(0) lgkmcnt(0)" ::: "memory");

    int row0 = rowptr[n], deg = rowptr[n + 1] - row0;
    const unsigned short* ql = q_lds[wv];

    float m = -__builtin_inff(), zr = 0.f, acc = 0.f;
    bool s0 = lane & 1, s1 = lane & 2, s2 = lane & 4;

    int i = 0;
    for (; i + 8 <= deg; i += 8) {
        float v[8], hv[8];
        #pragma unroll
        for (int j = 0; j < 8; ++j) {
            int p = epack[row0 + i + j];
            int s = p & 0xffff, r = p >> 16;
            hv[j] = bf2f(hbf[(size_t)s * DD + lane]);
            v[j]  = hv[j] * bf2f(ql[r * DD + lane]);
        }
        // interleaved reduce: 7 shuffles fold 8 values into lanes by j=lane&7
        float x0 = s0 ? v[1] : v[0], o0 = s0 ? v[0] : v[1];
        float x1 = s0 ? v[3] : v[2], o1 = s0 ? v[2] : v[3];
        float x2 = s0 ? v[5] : v[4], o2 = s0 ? v[4] : v[5];
        float x3 = s0 ? v[7] : v[6], o3 = s0 ? v[6] : v[7];
        x0 += __shfl_xor(o0, 1, 64);
        x1 += __shfl_xor(o1, 1, 64);
        x2 += __shfl_xor(o2, 1, 64);
        x3 += __shfl_xor(o3, 1, 64);
        float y0 = s1 ? x1 : x0, p0 = s1 ? x0 : x1;
        float y1 = s1 ? x3 : x2, p1 = s1 ? x2 : x3;
        y0 += __shfl_xor(p0, 2, 64);
        y1 += __shfl_xor(p1, 2, 64);
        float sj = s2 ? y1 : y0, q0 = s2 ? y0 : y1;
        sj += __shfl_xor(q0, 4, 64);
        sj += __shfl_xor(sj, 8, 64);
        sj += __shfl_xor(sj, 16, 64);
        sj += __shfl_xor(sj, 32, 64);
        // sj = score of edge j = lane&7, in every 8-lane group

        float cm = sj;
        cm = fmaxf(cm, __shfl_xor(cm, 1, 64));
        cm = fmaxf(cm, __shfl_xor(cm, 2, 64));
        cm = fmaxf(cm, __shfl_xor(cm, 4, 64));
        float mn = fmaxf(m, cm);
        float sc = __expf(m - mn);      // m=-inf first chunk -> 0
        float wgt = __expf(sj - mn);
        float zn = wgt;
        zn += __shfl_xor(zn, 1, 64);
        zn += __shfl_xor(zn, 2, 64);
        zn += __shfl_xor(zn, 4, 64);
        zr = zr * sc + zn;
        acc *= sc;
        #pragma unroll
        for (int j = 0; j < 8; ++j)
            acc += __shfl(wgt, j, 8) * hv[j];
        m = mn;
    }
    for (; i < deg; ++i) {
        int p = epack[row0 + i];
        int s = p & 0xffff, r = p >> 16;
        float hsv = bf2f(hbf[(size_t)s * DD + lane]);
        float v = hsv * bf2f(ql[r * DD + lane]);
        #pragma unroll
        for (int o = 32; o; o >>= 1) v += __shfl_xor(v, o, 64);
        float mn = fmaxf(m, v);
        float sc = __expf(m - mn);
        float wgt = __expf(v - mn);
        zr  = zr * sc + wgt;
        acc = acc * sc + wgt * hsv;
        m = mn;
    }
    h_nb[(size_t)n * DD + lane] = (deg > 0) ? acc / zr : 0.f;
}

// ---------- epilogue GEMM (f32) + bf16 shadow of new h ----------
__global__ __launch_bounds__(256) void k_out2(const float* __restrict__ h_nb,
                                              const float* __restrict__ ra,
                                              const float* __restrict__ rb,
                                              float* __restrict__ out,
                                              int off_in, int off_out,
                                              unsigned short* __restrict__ hbf) {
    __shared__ __align__(16) float v1s[64][68];
    __shared__ __align__(16) float v2s[64][68];
    __shared__ __align__(16) float ws[2][64][64];
    int t = threadIdx.x;
    int n0 = blockIdx.x * 64;

    for (int i = t; i < 1024; i += 256) {
        int ni = i >> 4, c4 = (i & 15) * 4;
        int n = n0 + ni;
        float4 hv = make_float4(0.f, 0.f, 0.f, 0.f);
        float4 nb = make_float4(0.f, 0.f, 0.f, 0.f);
        if (n < NN) {
            hv = *(const float4*)&out[(size_t)n * OSTRIDE + off_in + c4];
            nb = *(const float4*)&h_nb[(size_t)n * DD + c4];
        }
        v1s[c4 + 0][ni] = hv.x + nb.x;  v2s[c4 + 0][ni] = hv.x * nb.x;
        v1s[c4 + 1][ni] = hv.y + nb.y;  v2s[c4 + 1][ni] = hv.y * nb.y;
        v1s[c4 + 2][ni] = hv.z + nb.z;  v2s[c4 + 2][ni] = hv.z * nb.z;
        v1s[c4 + 3][ni] = hv.w + nb.w;  v2s[c4 + 3][ni] = hv.w * nb.w;
    }
    for (int i = t; i < 2048; i += 256) {
        const float* base = (i < 1024) ? ra : rb;
        int rem = i & 1023;
        float4 v = *(const float4*)&base[rem * 4];
        int k = rem >> 4, c4 = (rem & 15) * 4;
        *(float4*)&ws[i >> 10][k][c4] = v;
    }
    __syncthreads();

    int nd0 = (t >> 4) * 4;
    int c0  = (t & 15) * 4;
    float a1[4][4] = {}, a2[4][4] = {};
    #pragma unroll 8
    for (int k = 0; k < 64; ++k) {
        float4 h1 = *(const float4*)&v1s[k][nd0];
        float4 h2 = *(const float4*)&v2s[k][nd0];
        float4 wa = *(const float4*)&ws[0][k][c0];
        float4 wb = *(const float4*)&ws[1][k][c0];
        float x1[4] = {h1.x, h1.y, h1.z, h1.w};
        float x2[4] = {h2.x, h2.y, h2.z, h2.w};
        #pragma unroll
        for (int i = 0; i < 4; ++i) {
            a1[i][0] += x1[i] * wa.x; a1[i][1] += x1[i] * wa.y;
            a1[i][2] += x1[i] * wa.z; a1[i][3] += x1[i] * wa.w;
            a2[i][0] += x2[i] * wb.x; a2[i][1] += x2[i] * wb.y;
            a2[i][2] += x2[i] * wb.z; a2[i][3] += x2[i] * wb.w;
        }
    }
    #pragma unroll
    for (int i = 0; i < 4; ++i) {
        int n = n0 + nd0 + i;
        if (n >= NN) continue;
        float4 o;
        float* po = (float*)&o;
        #pragma unroll
        for (int j = 0; j < 4; ++j) {
            float u1 = a1[i][j], u2 = a2[i][j];
            u1 = u1 > 0.f ? u1 : 0.01f * u1;
            u2 = u2 > 0.f ? u2 : 0.01f * u2;
            po[j] = u1 + u2;
        }
        *(float4*)&out[(size_t)n * OSTRIDE + off_out + c0] = o;
        hbf[(size_t)n * DD + c0 + 0] = f2bf(o.x);
        hbf[(size_t)n * DD + c0 + 1] = f2bf(o.y);
        hbf[(size_t)n * DD + c0 + 2] = f2bf(o.z);
        hbf[(size_t)n * DD + c0 + 3] = f2bf(o.w);
    }
}

// ---------- launch ----------
extern "C" void kernel_launch(void* const* d_in, const int* in_sizes, int n_in,
                              void* d_out, int out_size, void* d_ws, size_t ws_size,
                              hipStream_t stream) {
    const int*   node_ids = (const int*)d_in[0];
    const int*   rel_ids  = (const int*)d_in[1];
    const int*   src      = (const int*)d_in[2];
    const int*   dst      = (const int*)d_in[3];
    const float* ent      = (const float*)d_in[4];
    const float* relE     = (const float*)d_in[5];
    const float* W[2]  = {(const float*)d_in[6], (const float*)d_in[7]};
    const float* ra[2] = {(const float*)d_in[8], (const float*)d_in[10]};
    const float* rb[2] = {(const float*)d_in[9], (const float*)d_in[11]};
    float* out = (float*)d_out;

    const size_t hnb_bytes    = (size_t)NN * DD * sizeof(float);            // 12.8 MB
    const size_t qbf_bytes    = (size_t)NN * NR * DD * sizeof(short);       // 102.4 MB
    const size_t hbf_bytes    = (size_t)NN * DD * sizeof(short);            // 6.4 MB
    const size_t wbf_bytes    = (size_t)NR * DD * DD * sizeof(short);       // 128 KB
    const size_t epack_bytes  = (size_t)NE * sizeof(int);                   // 3.2 MB
    const size_t rowptr_bytes = (size_t)(NN + 1) * sizeof(int);
    const size_t cnt_bytes    = (size_t)NN * sizeof(int);
    const size_t mask_bytes   = (size_t)NN * sizeof(int);

    char* p = (char*)d_ws;
    float*          h_nb   = (float*)p;          p += hnb_bytes;
    unsigned short* qbf    = (unsigned short*)p; p += qbf_bytes;
    unsigned short* hbf    = (unsigned short*)p; p += hbf_bytes;
    unsigned short* wbf    = (unsigned short*)p; p += wbf_bytes;
    unsigned short* wtbf   = (unsigned short*)p; p += wbf_bytes;
    int*            epack  = (int*)p;            p += epack_bytes;
    int*            rowptr = (int*)p;            p += rowptr_bytes;
    int*            cnt    = (int*)p;            p += cnt_bytes;
    size_t used = (size_t)(p - (char*)d_ws);
    int* relmask = (used + mask_bytes <= ws_size) ? (int*)p : nullptr;

    // ---- CSR build (shared by both layers) ----
    hipMemsetAsync(cnt, 0, cnt_bytes, stream);
    if (relmask) hipMemsetAsync(relmask, 0, mask_bytes, stream);
    k_deg <<<1024, 256, 0, stream>>>(dst, rel_ids, cnt, relmask);
    k_scan<<<1, 1024, 0, stream>>>(cnt, rowptr);
    k_fill<<<1024, 256, 0, stream>>>(dst, src, rel_ids, cnt, epack);

    // ---- h0 ----
    k_copy_h0<<<(NN * DD + 255) / 256, 256, 0, stream>>>(node_ids, ent, out, hbf);

    dim3 tq_grid(NR, (NN + 127) / 128);
    for (int L = 0; L < 2; ++L) {
        int off_in = L * DD;
        int off_out = (L + 1) * DD;

        k_wprep <<<(NR * DD * DD + 255) / 256, 256, 0, stream>>>(W[L], wbf, wtbf);
        k_transq4<<<tq_grid, 256, 0, stream>>>(hbf, wbf, wtbf, relE, relmask, qbf);
        k_fused4<<<(NN + 3) / 4, 256, 0, stream>>>(qbf, hbf, rowptr, epack, h_nb);
        k_out2  <<<(NN + 63) / 64, 256, 0, stream>>>(h_nb, ra[L], rb[L], out,
                                                     off_in, off_out, hbf);
    }
}

// Round 9
// 447.686 us; speedup vs baseline: 2.2007x; 1.2518x over previous
//
#include <hip/hip_runtime.h>
#include <hip/hip_bf16.h>
#include <math.h>

#define NN 50000
#define NE 800000
#define NR 16
#define DD 64
#define OSTRIDE 192   // 3*D concat output stride

typedef __attribute__((ext_vector_type(8))) short bf16x8;
typedef __attribute__((ext_vector_type(4))) float f32x4;

__device__ inline float tanh_fast(float x) {
    return 1.f - 2.f / (__expf(2.f * x) + 1.f);
}
__device__ inline unsigned short f2bf(float f) {   // RNE f32 -> bf16
    unsigned u = __float_as_uint(f);
    return (unsigned short)((u + 0x7fffu + ((u >> 16) & 1u)) >> 16);
}
__device__ inline float bf2f(unsigned short s) {
    return __uint_as_float((unsigned)s << 16);
}

// ---------- CSR build + per-node relation mask ----------
__global__ void k_deg(const int* __restrict__ dst, const int* __restrict__ rel,
                      int* __restrict__ cnt, int* __restrict__ relmask) {
    for (int e = blockIdx.x * blockDim.x + threadIdx.x; e < NE;
         e += gridDim.x * blockDim.x) {
        int d = dst[e];
        atomicAdd(&cnt[d], 1);
        if (relmask) atomicOr(&relmask[d], 1 << rel[e]);
    }
}

// hierarchical exclusive scan over cnt[NN] -> rowptr, cursor
__global__ __launch_bounds__(256) void k_scan1(const int* __restrict__ cnt,
                                               int* __restrict__ rowptr,
                                               int* __restrict__ bsum) {
    __shared__ int sh[256];
    int b = blockIdx.x, t = threadIdx.x;
    int i = b * 256 + t;
    int v = (i < NN) ? cnt[i] : 0;
    sh[t] = v;
    __syncthreads();
    #pragma unroll
    for (int o = 1; o < 256; o <<= 1) {
        int u = (t >= o) ? sh[t - o] : 0;
        __syncthreads();
        sh[t] += u;
        __syncthreads();
    }
    if (i < NN) rowptr[i] = sh[t] - v;     // local exclusive
    if (t == 255) bsum[b] = sh[255];
}

__global__ __launch_bounds__(256) void k_scan2(int* __restrict__ bsum, int nb) {
    __shared__ int sh[256];
    int t = threadIdx.x;
    int v = (t < nb) ? bsum[t] : 0;
    sh[t] = v;
    __syncthreads();
    #pragma unroll
    for (int o = 1; o < 256; o <<= 1) {
        int u = (t >= o) ? sh[t - o] : 0;
        __syncthreads();
        sh[t] += u;
        __syncthreads();
    }
    if (t < nb) bsum[t] = sh[t] - v;       // exclusive block offsets
}

__global__ __launch_bounds__(256) void k_scan3(int* __restrict__ rowptr,
                                               const int* __restrict__ bsum,
                                               int* __restrict__ cursor) {
    int b = blockIdx.x, t = threadIdx.x;
    int i = b * 256 + t;
    if (i < NN) {
        int v = rowptr[i] + bsum[b];
        rowptr[i] = v;
        cursor[i] = v;
    }
    if (i == 0) rowptr[NN] = NE;
}

// epack[pos] = src | (rel<<16)
__global__ void k_fill(const int* __restrict__ dst, const int* __restrict__ src,
                       const int* __restrict__ rel, int* __restrict__ cursor,
                       int* __restrict__ epack) {
    for (int e = blockIdx.x * blockDim.x + threadIdx.x; e < NE;
         e += gridDim.x * blockDim.x) {
        int pos = atomicAdd(&cursor[dst[e]], 1);
        epack[pos] = src[e] | (rel[e] << 16);
    }
}

// ---------- h0 gather (f32 out slice + bf16 shadow) ----------
__global__ void k_copy_h0(const int* __restrict__ node_ids,
                          const float* __restrict__ ent,
                          float* __restrict__ out,
                          unsigned short* __restrict__ hbf) {
    int i = blockIdx.x * blockDim.x + threadIdx.x;
    if (i >= NN * DD) return;
    int n = i >> 6, d = i & 63;
    float v = ent[(size_t)node_ids[n] * DD + d];
    out[(size_t)n * OSTRIDE + d] = v;
    hbf[(size_t)n * DD + d] = f2bf(v);
}

// ---------- W -> bf16 tables: wbf[r][d][E], wtbf[r][E][d] ----------
__global__ void k_wprep(const float* __restrict__ W, unsigned short* __restrict__ wbf,
                        unsigned short* __restrict__ wtbf) {
    int i = blockIdx.x * blockDim.x + threadIdx.x;   // 16*64*64 = 65536
    if (i >= NR * DD * DD) return;
    int r = i >> 12, rem = i & 4095, d = rem >> 6, E = rem & 63;
    unsigned short v = f2bf(W[i]);
    wbf[i] = v;
    wtbf[(r << 12) | (E << 6) | d] = v;
}

// ---------- q[n,r,:] = W_r @ tanh(h[n,:]@W_r + e_r), bf16 MFMA, 2 tiles/wave ----------
__global__ __launch_bounds__(256) void k_transq4(const unsigned short* __restrict__ hbf,
                                                 const unsigned short* __restrict__ wbf,
                                                 const unsigned short* __restrict__ wtbf,
                                                 const float* __restrict__ relE,
                                                 const int* __restrict__ relmask,
                                                 unsigned short* __restrict__ qbf) {
    __shared__ __align__(16) unsigned short u_lds[4][32][72];  // 144B rows, 16B-aligned
    int r  = blockIdx.x;
    int n0 = blockIdx.y * 128;
    int t  = threadIdx.x;
    int w  = t >> 6, l = t & 63;
    int l15 = l & 15, lg = l >> 4;
    int base = n0 + w * 32;

    int ar0 = base + l15;      if (ar0 >= NN) ar0 = NN - 1;
    int ar1 = base + 16 + l15; if (ar1 >= NN) ar1 = NN - 1;
    const unsigned short* ap0 = hbf + (size_t)ar0 * DD + lg * 8;
    const unsigned short* ap1 = hbf + (size_t)ar1 * DD + lg * 8;
    bf16x8 a00 = *(const bf16x8*)ap0;
    bf16x8 a01 = *(const bf16x8*)(ap0 + 32);
    bf16x8 a10 = *(const bf16x8*)ap1;
    bf16x8 a11 = *(const bf16x8*)(ap1 + 32);

    f32x4 acc[2][4];
    #pragma unroll
    for (int ti = 0; ti < 2; ++ti)
        #pragma unroll
        for (int nt = 0; nt < 4; ++nt) acc[ti][nt] = (f32x4){0.f, 0.f, 0.f, 0.f};

    const unsigned short* wtr = wtbf + (r << 12);
    #pragma unroll
    for (int nt = 0; nt < 4; ++nt) {
        const unsigned short* bp = wtr + (nt * 16 + l15) * DD + lg * 8;
        bf16x8 b0 = *(const bf16x8*)bp;
        bf16x8 b1 = *(const bf16x8*)(bp + 32);
        acc[0][nt] = __builtin_amdgcn_mfma_f32_16x16x32_bf16(a00, b0, acc[0][nt], 0, 0, 0);
        acc[0][nt] = __builtin_amdgcn_mfma_f32_16x16x32_bf16(a01, b1, acc[0][nt], 0, 0, 0);
        acc[1][nt] = __builtin_amdgcn_mfma_f32_16x16x32_bf16(a10, b0, acc[1][nt], 0, 0, 0);
        acc[1][nt] = __builtin_amdgcn_mfma_f32_16x16x32_bf16(a11, b1, acc[1][nt], 0, 0, 0);
    }

    #pragma unroll
    for (int nt = 0; nt < 4; ++nt) {
        int E = nt * 16 + l15;
        float er = relE[r * DD + E];
        #pragma unroll
        for (int ti = 0; ti < 2; ++ti)
            #pragma unroll
            for (int reg = 0; reg < 4; ++reg)
                u_lds[w][ti * 16 + lg * 4 + reg][E] = f2bf(tanh_fast(acc[ti][nt][reg] + er));
    }
    asm volatile("s_waitcnt lgkmcnt(0)" ::: "memory");

    const unsigned short* up0 = &u_lds[w][l15][lg * 8];
    const unsigned short* up1 = &u_lds[w][16 + l15][lg * 8];
    bf16x8 u00 = *(const bf16x8*)up0;
    bf16x8 u01 = *(const bf16x8*)(up0 + 32);
    bf16x8 u10 = *(const bf16x8*)up1;
    bf16x8 u11 = *(const bf16x8*)(up1 + 32);

    f32x4 q4[2][4];
    #pragma unroll
    for (int ti = 0; ti < 2; ++ti)
        #pragma unroll
        for (int nt = 0; nt < 4; ++nt) q4[ti][nt] = (f32x4){0.f, 0.f, 0.f, 0.f};

    const unsigned short* wr = wbf + (r << 12);
    #pragma unroll
    for (int nt = 0; nt < 4; ++nt) {
        const unsigned short* bp = wr + (nt * 16 + l15) * DD + lg * 8;
        bf16x8 b0 = *(const bf16x8*)bp;
        bf16x8 b1 = *(const bf16x8*)(bp + 32);
        q4[0][nt] = __builtin_amdgcn_mfma_f32_16x16x32_bf16(u00, b0, q4[0][nt], 0, 0, 0);
        q4[0][nt] = __builtin_amdgcn_mfma_f32_16x16x32_bf16(u01, b1, q4[0][nt], 0, 0, 0);
        q4[1][nt] = __builtin_amdgcn_mfma_f32_16x16x32_bf16(u10, b0, q4[1][nt], 0, 0, 0);
        q4[1][nt] = __builtin_amdgcn_mfma_f32_16x16x32_bf16(u11, b1, q4[1][nt], 0, 0, 0);
    }

    #pragma unroll
    for (int ti = 0; ti < 2; ++ti) {
        #pragma unroll
        for (int reg = 0; reg < 4; ++reg) {
            int node = base + ti * 16 + lg * 4 + reg;
            if (node < NN) {
                int msk = relmask ? relmask[node] : 0xffff;
                if ((msk >> r) & 1) {
                    unsigned short* qp = qbf + ((size_t)node * NR + r) * DD + l15;
                    #pragma unroll
                    for (int nt = 0; nt < 4; ++nt)
                        qp[nt * 16] = f2bf(q4[ti][nt][reg]);
                }
            }
        }
    }
}

// ---------- fused attention + softmax + aggregate (one wave per dst node) ----------
__global__ __launch_bounds__(256) void k_fused4(const unsigned short* __restrict__ qbf,
                                                const unsigned short* __restrict__ hbf,
                                                const int* __restrict__ rowptr,
                                                const int* __restrict__ epack,
                                                float* __restrict__ h_nb) {
    __shared__ __align__(16) unsigned short q_lds[4][1024];   // per-wave 2KB
    int wv = threadIdx.x >> 6;
    int n = blockIdx.x * 4 + wv;
    if (n >= NN) return;
    int lane = threadIdx.x & 63;

    {
        const uint4* s4 = (const uint4*)(qbf + (size_t)n * NR * DD);
        uint4* d4 = (uint4*)q_lds[wv];
        d4[lane]      = s4[lane];
        d4[lane + 64] = s4[lane + 64];
    }
    asm volatile("s_waitcnt vmcnt(0) lgkmcnt(0)" ::: "memory");

    int row0 = rowptr[n], deg = rowptr[n + 1] - row0;
    const unsigned short* ql = q_lds[wv];

    float m = -__builtin_inff(), zr = 0.f, acc = 0.f;
    bool s0 = lane & 1, s1 = lane & 2, s2 = lane & 4;

    int i = 0;
    for (; i + 8 <= deg; i += 8) {
        float v[8], hv[8];
        #pragma unroll
        for (int j = 0; j < 8; ++j) {
            int p = epack[row0 + i + j];
            int s = p & 0xffff, r = p >> 16;
            hv[j] = bf2f(hbf[(size_t)s * DD + lane]);
            v[j]  = hv[j] * bf2f(ql[r * DD + lane]);
        }
        float x0 = s0 ? v[1] : v[0], o0 = s0 ? v[0] : v[1];
        float x1 = s0 ? v[3] : v[2], o1 = s0 ? v[2] : v[3];
        float x2 = s0 ? v[5] : v[4], o2 = s0 ? v[4] : v[5];
        float x3 = s0 ? v[7] : v[6], o3 = s0 ? v[6] : v[7];
        x0 += __shfl_xor(o0, 1, 64);
        x1 += __shfl_xor(o1, 1, 64);
        x2 += __shfl_xor(o2, 1, 64);
        x3 += __shfl_xor(o3, 1, 64);
        float y0 = s1 ? x1 : x0, p0 = s1 ? x0 : x1;
        float y1 = s1 ? x3 : x2, p1 = s1 ? x2 : x3;
        y0 += __shfl_xor(p0, 2, 64);
        y1 += __shfl_xor(p1, 2, 64);
        float sj = s2 ? y1 : y0, q0 = s2 ? y0 : y1;
        sj += __shfl_xor(q0, 4, 64);
        sj += __shfl_xor(sj, 8, 64);
        sj += __shfl_xor(sj, 16, 64);
        sj += __shfl_xor(sj, 32, 64);

        float cm = sj;
        cm = fmaxf(cm, __shfl_xor(cm, 1, 64));
        cm = fmaxf(cm, __shfl_xor(cm, 2, 64));
        cm = fmaxf(cm, __shfl_xor(cm, 4, 64));
        float mn = fmaxf(m, cm);
        float sc = __expf(m - mn);
        float wgt = __expf(sj - mn);
        float zn = wgt;
        zn += __shfl_xor(zn, 1, 64);
        zn += __shfl_xor(zn, 2, 64);
        zn += __shfl_xor(zn, 4, 64);
        zr = zr * sc + zn;
        acc *= sc;
        #pragma unroll
        for (int j = 0; j < 8; ++j)
            acc += __shfl(wgt, j, 8) * hv[j];
        m = mn;
    }
    for (; i < deg; ++i) {
        int p = epack[row0 + i];
        int s = p & 0xffff, r = p >> 16;
        float hsv = bf2f(hbf[(size_t)s * DD + lane]);
        float v = hsv * bf2f(ql[r * DD + lane]);
        #pragma unroll
        for (int o = 32; o; o >>= 1) v += __shfl_xor(v, o, 64);
        float mn = fmaxf(m, v);
        float sc = __expf(m - mn);
        float wgt = __expf(v - mn);
        zr  = zr * sc + wgt;
        acc = acc * sc + wgt * hsv;
        m = mn;
    }
    h_nb[(size_t)n * DD + lane] = (deg > 0) ? acc / zr : 0.f;
}

// ---------- epilogue GEMM (f32) + bf16 shadow of new h ----------
__global__ __launch_bounds__(256) void k_out2(const float* __restrict__ h_nb,
                                              const float* __restrict__ ra,
                                              const float* __restrict__ rb,
                                              float* __restrict__ out,
                                              int off_in, int off_out,
                                              unsigned short* __restrict__ hbf) {
    __shared__ __align__(16) float v1s[64][68];
    __shared__ __align__(16) float v2s[64][68];
    __shared__ __align__(16) float ws[2][64][64];
    int t = threadIdx.x;
    int n0 = blockIdx.x * 64;

    for (int i = t; i < 1024; i += 256) {
        int ni = i >> 4, c4 = (i & 15) * 4;
        int n = n0 + ni;
        float4 hv = make_float4(0.f, 0.f, 0.f, 0.f);
        float4 nb = make_float4(0.f, 0.f, 0.f, 0.f);
        if (n < NN) {
            hv = *(const float4*)&out[(size_t)n * OSTRIDE + off_in + c4];
            nb = *(const float4*)&h_nb[(size_t)n * DD + c4];
        }
        v1s[c4 + 0][ni] = hv.x + nb.x;  v2s[c4 + 0][ni] = hv.x * nb.x;
        v1s[c4 + 1][ni] = hv.y + nb.y;  v2s[c4 + 1][ni] = hv.y * nb.y;
        v1s[c4 + 2][ni] = hv.z + nb.z;  v2s[c4 + 2][ni] = hv.z * nb.z;
        v1s[c4 + 3][ni] = hv.w + nb.w;  v2s[c4 + 3][ni] = hv.w * nb.w;
    }
    for (int i = t; i < 2048; i += 256) {
        const float* base = (i < 1024) ? ra : rb;
        int rem = i & 1023;
        float4 v = *(const float4*)&base[rem * 4];
        int k = rem >> 4, c4 = (rem & 15) * 4;
        *(float4*)&ws[i >> 10][k][c4] = v;
    }
    __syncthreads();

    int nd0 = (t >> 4) * 4;
    int c0  = (t & 15) * 4;
    float a1[4][4] = {}, a2[4][4] = {};
    #pragma unroll 8
    for (int k = 0; k < 64; ++k) {
        float4 h1 = *(const float4*)&v1s[k][nd0];
        float4 h2 = *(const float4*)&v2s[k][nd0];
        float4 wa = *(const float4*)&ws[0][k][c0];
        float4 wb = *(const float4*)&ws[1][k][c0];
        float x1[4] = {h1.x, h1.y, h1.z, h1.w};
        float x2[4] = {h2.x, h2.y, h2.z, h2.w};
        #pragma unroll
        for (int i = 0; i < 4; ++i) {
            a1[i][0] += x1[i] * wa.x; a1[i][1] += x1[i] * wa.y;
            a1[i][2] += x1[i] * wa.z; a1[i][3] += x1[i] * wa.w;
            a2[i][0] += x2[i] * wb.x; a2[i][1] += x2[i] * wb.y;
            a2[i][2] += x2[i] * wb.z; a2[i][3] += x2[i] * wb.w;
        }
    }
    #pragma unroll
    for (int i = 0; i < 4; ++i) {
        int n = n0 + nd0 + i;
        if (n >= NN) continue;
        float4 o;
        float* po = (float*)&o;
        #pragma unroll
        for (int j = 0; j < 4; ++j) {
            float u1 = a1[i][j], u2 = a2[i][j];
            u1 = u1 > 0.f ? u1 : 0.01f * u1;
            u2 = u2 > 0.f ? u2 : 0.01f * u2;
            po[j] = u1 + u2;
        }
        *(float4*)&out[(size_t)n * OSTRIDE + off_out + c0] = o;
        hbf[(size_t)n * DD + c0 + 0] = f2bf(o.x);
        hbf[(size_t)n * DD + c0 + 1] = f2bf(o.y);
        hbf[(size_t)n * DD + c0 + 2] = f2bf(o.z);
        hbf[(size_t)n * DD + c0 + 3] = f2bf(o.w);
    }
}

// ---------- launch ----------
extern "C" void kernel_launch(void* const* d_in, const int* in_sizes, int n_in,
                              void* d_out, int out_size, void* d_ws, size_t ws_size,
                              hipStream_t stream) {
    const int*   node_ids = (const int*)d_in[0];
    const int*   rel_ids  = (const int*)d_in[1];
    const int*   src      = (const int*)d_in[2];
    const int*   dst      = (const int*)d_in[3];
    const float* ent      = (const float*)d_in[4];
    const float* relE     = (const float*)d_in[5];
    const float* W[2]  = {(const float*)d_in[6], (const float*)d_in[7]};
    const float* ra[2] = {(const float*)d_in[8], (const float*)d_in[10]};
    const float* rb[2] = {(const float*)d_in[9], (const float*)d_in[11]};
    float* out = (float*)d_out;

    const size_t hnb_bytes    = (size_t)NN * DD * sizeof(float);            // 12.8 MB
    const size_t qbf_bytes    = (size_t)NN * NR * DD * sizeof(short);       // 102.4 MB
    const size_t hbf_bytes    = (size_t)NN * DD * sizeof(short);            // 6.4 MB
    const size_t wbf_bytes    = (size_t)NR * DD * DD * sizeof(short);       // 128 KB
    const size_t epack_bytes  = (size_t)NE * sizeof(int);                   // 3.2 MB
    const size_t rowptr_bytes = (size_t)(NN + 1) * sizeof(int);
    const size_t cnt_bytes    = (size_t)NN * sizeof(int);
    const size_t mask_bytes   = (size_t)NN * sizeof(int);
    const int    NB_SCAN      = (NN + 255) / 256;   // 196
    const size_t bsum_bytes   = (size_t)256 * sizeof(int);

    char* p = (char*)d_ws;
    float*          h_nb   = (float*)p;          p += hnb_bytes;
    unsigned short* qbf    = (unsigned short*)p; p += qbf_bytes;
    unsigned short* hbf    = (unsigned short*)p; p += hbf_bytes;
    unsigned short* wbf    = (unsigned short*)p; p += wbf_bytes;
    unsigned short* wtbf   = (unsigned short*)p; p += wbf_bytes;
    int*            epack  = (int*)p;            p += epack_bytes;
    int*            rowptr = (int*)p;            p += rowptr_bytes;
    int*            cnt    = (int*)p;            p += cnt_bytes;
    int*            bsum   = (int*)p;            p += bsum_bytes;
    size_t used = (size_t)(p - (char*)d_ws);
    int* relmask = (used + mask_bytes <= ws_size) ? (int*)p : nullptr;

    // ---- CSR build (shared by both layers) ----
    hipMemsetAsync(cnt, 0, cnt_bytes, stream);
    if (relmask) hipMemsetAsync(relmask, 0, mask_bytes, stream);
    k_deg  <<<1024, 256, 0, stream>>>(dst, rel_ids, cnt, relmask);
    k_scan1<<<NB_SCAN, 256, 0, stream>>>(cnt, rowptr, bsum);
    k_scan2<<<1, 256, 0, stream>>>(bsum, NB_SCAN);
    k_scan3<<<NB_SCAN, 256, 0, stream>>>(rowptr, bsum, cnt);
    k_fill <<<1024, 256, 0, stream>>>(dst, src, rel_ids, cnt, epack);

    // ---- h0 ----
    k_copy_h0<<<(NN * DD + 255) / 256, 256, 0, stream>>>(node_ids, ent, out, hbf);

    dim3 tq_grid(NR, (NN + 127) / 128);
    for (int L = 0; L < 2; ++L) {
        int off_in = L * DD;
        int off_out = (L + 1) * DD;

        k_wprep <<<(NR * DD * DD + 255) / 256, 256, 0, stream>>>(W[L], wbf, wtbf);
        k_transq4<<<tq_grid, 256, 0, stream>>>(hbf, wbf, wtbf, relE, relmask, qbf);
        k_fused4<<<(NN + 3) / 4, 256, 0, stream>>>(qbf, hbf, rowptr, epack, h_nb);
        k_out2  <<<(NN + 63) / 64, 256, 0, stream>>>(h_nb, ra[L], rb[L], out,
                                                     off_in, off_out, hbf);
    }
}